// Round 5
// baseline (153.409 us; speedup 1.0000x reference)
//
#include <hip/hip_runtime.h>

#define BROWS 16384
#define DDIM  512
#define NEXP  16
#define HDIM  128
#define ODIM  512

typedef __attribute__((ext_vector_type(8))) short bf16x8;
typedef __attribute__((ext_vector_type(4))) float f32x4;

typedef const __attribute__((address_space(1))) unsigned GA;
typedef __attribute__((address_space(3))) unsigned LA;
#define GLD16(g, l) __builtin_amdgcn_global_load_lds((GA*)(g), (LA*)(l), 16, 0, 0)

static __device__ __forceinline__ unsigned short f2bf(float f) {
    union { float f; unsigned u; } v; v.f = f;
    unsigned r = v.u + 0x7fffu + ((v.u >> 16) & 1u);
    return (unsigned short)(r >> 16);
}
static __device__ __forceinline__ float bf2f(unsigned short h) {
    union { unsigned u; float f; } v; v.u = ((unsigned)h) << 16;
    return v.f;
}

// ---------------- gW -> transposed f32 [16][512] ----------------
__global__ __launch_bounds__(256)
void gwt_prep(const float* __restrict__ in, float* __restrict__ out) {
    int i = blockIdx.x * 256 + threadIdx.x;   // 8192 elems
    int d = i >> 4, e = i & 15;
    out[e * 512 + d] = in[i];
}

// ---------------- W1 -> blocked bf16 [e][ks=8][c=128][k=64] ----------------
__global__ __launch_bounds__(256)
void w1_prep(const float* __restrict__ in, unsigned short* __restrict__ out) {
    __shared__ float tile[64][33];
    int e = blockIdx.z;
    int ks = blockIdx.y;
    int cb = blockIdx.x * 32;
    const float* src = in + ((size_t)e * 512 + ks * 64) * 128 + cb;
    int c = threadIdx.x & 31, r8 = threadIdx.x >> 5;
    #pragma unroll
    for (int p = 0; p < 8; ++p)
        tile[p * 8 + r8][c] = src[(size_t)(p * 8 + r8) * 128 + c];
    __syncthreads();
    int k = threadIdx.x & 63, c4 = threadIdx.x >> 6;
    unsigned short* dst = out + (((size_t)e * 8 + ks) * 128 + cb) * 64;
    #pragma unroll
    for (int p = 0; p < 8; ++p)
        dst[(size_t)(c4 + p * 4) * 64 + k] = f2bf(tile[k][c4 + p * 4]);
}

// ---------------- transpose W2 to bf16 [e][O][H] ----------------
__global__ __launch_bounds__(256)
void transpose_to_bf16(const float* __restrict__ in, unsigned short* __restrict__ out, int R, int C) {
    __shared__ float tile[32][33];
    int e = blockIdx.z;
    in  += (size_t)e * R * C;
    out += (size_t)e * R * C;
    int c0 = blockIdx.x * 32, r0 = blockIdx.y * 32;
    for (int i = threadIdx.y; i < 32; i += 8)
        tile[i][threadIdx.x] = in[(size_t)(r0 + i) * C + c0 + threadIdx.x];
    __syncthreads();
    for (int i = threadIdx.y; i < 32; i += 8)
        out[(size_t)(c0 + i) * R + r0 + threadIdx.x] = f2bf(tile[threadIdx.x][i]);
}

// ---------------- gating (fused with x->bf16 conversion) ----------------
// 1024 blocks x 256 threads; 16 rows/block, 4 rows/wave; gwT read from L2.
__global__ __launch_bounds__(256, 6)
void gate_kernel(const float* __restrict__ x, const float* __restrict__ gwT,
                 const float* __restrict__ gb,
                 int* cnt, float* ent_acc, int* bucket, int* topk_e, float* topk_w,
                 unsigned short* __restrict__ xb) {
    __shared__ int lcnt[16];
    __shared__ int gbase[16];
    __shared__ int entpack[32];
    __shared__ float entf;

    int tid = threadIdx.x;
    if (tid < 16) lcnt[tid] = 0;
    if (tid == 0) entf = 0.f;
    __syncthreads();

    int wave = tid >> 6, lane = tid & 63;
    int ds = lane & 31, rg = lane >> 5;
    int wrow = blockIdx.x * 16 + wave * 4 + rg * 2;   // rows: wrow, wrow+1

    // all 8 x loads issued up front (independent, in flight together)
    float4 xv[2][4];
    #pragma unroll
    for (int rr = 0; rr < 2; ++rr)
        #pragma unroll
        for (int di = 0; di < 4; ++di)
            xv[rr][di] = *reinterpret_cast<const float4*>(x + (size_t)(wrow + rr) * DDIM + ds * 4 + di * 128);

    // fused x -> bf16 write
    #pragma unroll
    for (int rr = 0; rr < 2; ++rr)
        #pragma unroll
        for (int di = 0; di < 4; ++di) {
            uint2 p;
            p.x = (unsigned)f2bf(xv[rr][di].x) | ((unsigned)f2bf(xv[rr][di].y) << 16);
            p.y = (unsigned)f2bf(xv[rr][di].z) | ((unsigned)f2bf(xv[rr][di].w) << 16);
            *reinterpret_cast<uint2*>(xb + (size_t)(wrow + rr) * DDIM + ds * 4 + di * 128) = p;
        }

    float acc[2][16];
    #pragma unroll
    for (int rr = 0; rr < 2; ++rr)
        #pragma unroll
        for (int e = 0; e < 16; ++e) acc[rr][e] = 0.f;

    const float4* gw4 = reinterpret_cast<const float4*>(gwT);
    #pragma unroll
    for (int di = 0; di < 4; ++di) {
        #pragma unroll
        for (int e = 0; e < 16; ++e) {
            float4 g = gw4[e * 128 + ds + di * 32];   // L2-resident
            #pragma unroll
            for (int rr = 0; rr < 2; ++rr) {
                acc[rr][e] = fmaf(xv[rr][di].x, g.x, acc[rr][e]);
                acc[rr][e] = fmaf(xv[rr][di].y, g.y, acc[rr][e]);
                acc[rr][e] = fmaf(xv[rr][di].z, g.z, acc[rr][e]);
                acc[rr][e] = fmaf(xv[rr][di].w, g.w, acc[rr][e]);
            }
        }
    }

    // butterfly reduce across the 32 d-slice lanes; all lanes get sums
    #pragma unroll
    for (int rr = 0; rr < 2; ++rr)
        #pragma unroll
        for (int e = 0; e < 16; ++e) {
            float v = acc[rr][e];
            v += __shfl_xor(v, 1);  v += __shfl_xor(v, 2);
            v += __shfl_xor(v, 4);  v += __shfl_xor(v, 8);
            v += __shfl_xor(v, 16);
            acc[rr][e] = v;
        }

    if (ds < 2) {
        int rr = ds;
        int row = wrow + rr;
        float sc[16];
        #pragma unroll
        for (int e = 0; e < 16; ++e) sc[e] = acc[rr][e] + gb[e];
        float v0 = -1e30f, v1 = -1e30f; int i0 = 0, i1 = 0;
        #pragma unroll
        for (int k = 0; k < 16; ++k) {
            float sv = sc[k];
            if (sv > v0) { v1 = v0; i1 = i0; v0 = sv; i0 = k; }
            else if (sv > v1) { v1 = sv; i1 = k; }
        }
        float Z = 0.f, S1 = 0.f;
        #pragma unroll
        for (int k = 0; k < 16; ++k) {
            float t = sc[k] - v0;
            float ex = expf(t);
            Z += ex; S1 = fmaf(ex, t, S1);
        }
        float entloc = logf(Z) - S1 / Z;
        float w0 = 1.0f / (1.0f + expf(v1 - v0));
        topk_e[row * 2]     = i0;
        topk_e[row * 2 + 1] = i1;
        topk_w[row * 2]     = w0;
        topk_w[row * 2 + 1] = 1.0f - w0;
        int ib = wave * 4 + rg * 2 + rr;   // [0,16)
        int lp0 = atomicAdd(&lcnt[i0], 1);
        entpack[ib * 2]     = (row << 1) | (i0 << 15) | (lp0 << 19);
        int lp1 = atomicAdd(&lcnt[i1], 1);
        entpack[ib * 2 + 1] = ((row << 1) | 1) | (i1 << 15) | (lp1 << 19);
        atomicAdd(&entf, entloc);
    }
    __syncthreads();
    if (tid < 16) gbase[tid] = atomicAdd(&cnt[tid], lcnt[tid]);
    if (tid == 0) atomicAdd(ent_acc, entf);
    __syncthreads();
    if (tid < 32) {
        int p = entpack[tid];
        int rowslot = p & 0x7FFF;
        int e = (p >> 15) & 15;
        int lpos = p >> 19;
        bucket[e * BROWS + gbase[e] + lpos] = rowslot;
    }
}

// ---------------- aux loss ----------------
__global__ void aux_kernel(const int* __restrict__ cnt, const float* __restrict__ ent_acc,
                           float* __restrict__ outp) {
    if (threadIdx.x == 0 && blockIdx.x == 0) {
        float lb = 0.f;
        for (int k = 0; k < 16; ++k) {
            float u = (float)cnt[k] * (1.f / 16384.f) - 0.0625f;
            lb += u * u;
        }
        lb *= (1.f / 16.f);
        float ment = ent_acc[0] * (1.f / 16384.f);
        outp[0] = lb - 0.1f * ment;
    }
}

// ---------------- grouped sparse FFN, pipelined ----------------
__global__ __launch_bounds__(256, 2)
void ffn_kernel(const unsigned short* __restrict__ xb,
                const unsigned short* __restrict__ w1b,   // [E][8][128][64] bf16
                const unsigned short* __restrict__ w2t,   // [E][O][H] bf16
                const float* __restrict__ b1, const float* __restrict__ ln_g,
                const float* __restrict__ ln_b, const float* __restrict__ topk_w,
                const int* __restrict__ cnt, const int* __restrict__ bucket,
                unsigned short* __restrict__ contrib) {
    int e = blockIdx.x >> 6;
    int t = blockIdx.x & 63;
    int n = cnt[e];
    int base = t * 64;
    if (base >= n) return;
    int rows = n - base; if (rows > 64) rows = 64;

    __shared__ __align__(16) char smem[51712];

    const int tid = threadIdx.x;
    const int wave = tid >> 6, lane = tid & 63;
    const int l15 = lane & 15, l4 = lane >> 4;
    const int bbase = e * BROWS + base;

    if (tid < 64) {
        int idx = tid < rows ? tid : (rows - 1);
        int rs = bucket[bbase + idx];
        *(int*)(smem + 51200 + tid * 4) = rs;
        *(float*)(smem + 51456 + tid * 4) = topk_w[rs];
    }

    const int lsw = (((lane & 7) ^ ((lane >> 3) & 7)) << 4);
    int ar0 = wave * 16 + (lane >> 3);
    int ar1 = ar0 + 8;
    size_t grow0 = (size_t)(bucket[bbase + (ar0 < rows ? ar0 : rows - 1)] >> 1) * 1024;
    size_t grow1 = (size_t)(bucket[bbase + (ar1 < rows ? ar1 : rows - 1)] >> 1) * 1024;
    const char* xbp = (const char*)xb;
    const char* w1e = (const char*)w1b + (size_t)e * 131072;
    const char* w2e = (const char*)w2t + (size_t)e * 131072;
    const int sw2e = (((lane & 15) ^ (lane >> 4)) << 4);
    const int sw2o = sw2e ^ 64;

#define STAGE1(ks_, buf_) do { \
    char* ab_ = smem + (buf_) * 8192; \
    char* bb_ = smem + 16384 + (buf_) * 16384; \
    GLD16(xbp + grow0 + (ks_) * 128 + lsw, ab_ + (wave * 2 + 0) * 1024); \
    GLD16(xbp + grow1 + (ks_) * 128 + lsw, ab_ + (wave * 2 + 1) * 1024); \
    const char* s1_ = w1e + (ks_) * 16384 + ((lane >> 3) << 7) + lsw; \
    GLD16(s1_ + (wave * 4 + 0) * 1024, bb_ + (wave * 4 + 0) * 1024); \
    GLD16(s1_ + (wave * 4 + 1) * 1024, bb_ + (wave * 4 + 1) * 1024); \
    GLD16(s1_ + (wave * 4 + 2) * 1024, bb_ + (wave * 4 + 2) * 1024); \
    GLD16(s1_ + (wave * 4 + 3) * 1024, bb_ + (wave * 4 + 3) * 1024); \
} while (0)

#define STAGE2(ns_, buf_) do { \
    char* bb_ = smem + 16384 + (buf_) * 16384; \
    const char* s2_ = w2e + (size_t)(ns_) * 16384 + ((lane >> 4) << 8); \
    GLD16(s2_ + (wave * 4 + 0) * 1024 + sw2e, bb_ + (wave * 4 + 0) * 1024); \
    GLD16(s2_ + (wave * 4 + 1) * 1024 + sw2o, bb_ + (wave * 4 + 1) * 1024); \
    GLD16(s2_ + (wave * 4 + 2) * 1024 + sw2e, bb_ + (wave * 4 + 2) * 1024); \
    GLD16(s2_ + (wave * 4 + 3) * 1024 + sw2o, bb_ + (wave * 4 + 3) * 1024); \
} while (0)

    // ================= GEMM1: h = x_tile @ W1[e] =================
    STAGE1(0, 0);
    f32x4 acc1[4][2];
    #pragma unroll
    for (int r = 0; r < 4; ++r)
        #pragma unroll
        for (int c = 0; c < 2; ++c)
            acc1[r][c] = (f32x4){0.f, 0.f, 0.f, 0.f};

    #pragma unroll
    for (int ks = 0; ks < 8; ++ks) {
        const int cur = ks & 1;
        if (ks < 7) {
            STAGE1(ks + 1, cur ^ 1);
            asm volatile("s_waitcnt vmcnt(6)" ::: "memory");
        } else {
            asm volatile("s_waitcnt vmcnt(0)" ::: "memory");
        }
        asm volatile("s_barrier" ::: "memory");
        const char* ab = smem + cur * 8192;
        const char* bb = smem + 16384 + cur * 16384;
        #pragma unroll
        for (int ks2 = 0; ks2 < 2; ++ks2) {
            const int cb = (((ks2 * 4 + l4) ^ (l15 & 7)) << 4);
            bf16x8 a[4], bg[2];
            #pragma unroll
            for (int r = 0; r < 4; ++r)
                a[r] = *(const bf16x8*)(ab + (r * 16 + l15) * 128 + cb);
            bg[0] = *(const bf16x8*)(bb + (wave * 32 + l15) * 128 + cb);
            bg[1] = *(const bf16x8*)(bb + (wave * 32 + 16 + l15) * 128 + cb);
            #pragma unroll
            for (int r = 0; r < 4; ++r) {
                acc1[r][0] = __builtin_amdgcn_mfma_f32_16x16x32_bf16(a[r], bg[0], acc1[r][0], 0, 0, 0);
                acc1[r][1] = __builtin_amdgcn_mfma_f32_16x16x32_bf16(a[r], bg[1], acc1[r][1], 0, 0, 0);
            }
        }
        asm volatile("s_waitcnt lgkmcnt(0)\n\ts_barrier" ::: "memory");
    }

    // kick off first W2 slice while we do GELU/LN
    STAGE2(0, 0);

    // ================= bias + exact GELU (in regs) + LN partials =================
    const float* b1e = b1 + e * HDIM;
    const int c0 = wave * 32 + l15, c1 = c0 + 16;
    float bias0 = b1e[c0], bias1 = b1e[c1];
    #pragma unroll
    for (int r = 0; r < 4; ++r)
        #pragma unroll
        for (int i = 0; i < 4; ++i) {
            int row = r * 16 + l4 * 4 + i;
            float v0 = acc1[r][0][i] + bias0;
            float v1 = acc1[r][1][i] + bias1;
            v0 = 0.5f * v0 * (1.0f + erff(v0 * 0.70710678f));
            v1 = 0.5f * v1 * (1.0f + erff(v1 * 0.70710678f));
            acc1[r][0][i] = v0; acc1[r][1][i] = v1;
            float s = v0 + v1, ss = v0 * v0 + v1 * v1;
            s  += __shfl_xor(s, 1);  s  += __shfl_xor(s, 2);
            s  += __shfl_xor(s, 4);  s  += __shfl_xor(s, 8);
            ss += __shfl_xor(ss, 1); ss += __shfl_xor(ss, 2);
            ss += __shfl_xor(ss, 4); ss += __shfl_xor(ss, 8);
            if (l15 == 0) {
                *(float*)(smem + 49152 + row * 32 + wave * 8)     = s;
                *(float*)(smem + 49152 + row * 32 + wave * 8 + 4) = ss;
            }
        }
    asm volatile("s_waitcnt lgkmcnt(0)\n\ts_barrier" ::: "memory");

    // ================= LN apply (gate weight folded in) -> h_ln bf16 swizzled =================
    {
        const float* lge = ln_g + e * HDIM;
        const float* lbe = ln_b + e * HDIM;
        float g0 = lge[c0], g1 = lge[c1], be0 = lbe[c0], be1 = lbe[c1];
        #pragma unroll
        for (int r = 0; r < 4; ++r)
            #pragma unroll
            for (int i = 0; i < 4; ++i) {
                int row = r * 16 + l4 * 4 + i;
                float4 p0 = *(const float4*)(smem + 49152 + row * 32);
                float4 p1 = *(const float4*)(smem + 49152 + row * 32 + 16);
                float s  = p0.x + p0.z + p1.x + p1.z;
                float ss = p0.y + p0.w + p1.y + p1.w;
                float mean = s * 0.0078125f;
                float var  = fmaf(-mean, mean, ss * 0.0078125f);
                float rstd = rsqrtf(var + 1e-5f);
                float w = *(const float*)(smem + 51456 + row * 4);
                float h0 = ((acc1[r][0][i] - mean) * rstd * g0 + be0) * w;
                float h1 = ((acc1[r][1][i] - mean) * rstd * g1 + be1) * w;
                int wr = (row & 7) << 4;
                *(unsigned short*)(smem + row * 256 + ((c0 * 2) ^ wr)) = f2bf(h0);
                *(unsigned short*)(smem + row * 256 + ((c1 * 2) ^ wr)) = f2bf(h1);
            }
    }
    asm volatile("s_waitcnt lgkmcnt(0)\n\ts_barrier" ::: "memory");

    // ================= hoist GEMM2 A fragments to registers =================
    bf16x8 A2[4][4];
    #pragma unroll
    for (int r = 0; r < 4; ++r)
        #pragma unroll
        for (int kk = 0; kk < 4; ++kk)
            A2[r][kk] = *(const bf16x8*)(smem + (r * 16 + l15) * 256 + ((((kk * 4 + l4) ^ (l15 & 7))) << 4));
    asm volatile("s_waitcnt lgkmcnt(0)\n\ts_barrier" ::: "memory");   // h_ln region now reusable as patches

    // ================= GEMM2: contrib = h_ln @ W2[e], barrier-free =================
    STAGE2(1, 1);
    char* patch = smem + wave * 3072;   // 64 rows x 48B (16 cols bf16 + pad)
    const int rsoff = (*(const int*)(smem + 51200 + lane * 4)) << 10;
    char* cw = (char*)contrib + rsoff + wave * 32;

    #pragma unroll
    for (int ns = 0; ns < 8; ++ns) {
        if (ns < 7) {
            asm volatile("s_waitcnt lgkmcnt(0)" ::: "memory");
            if (ns > 0) STAGE2(ns + 1, (ns + 1) & 1);
        }
        if (ns == 0)      asm volatile("s_waitcnt vmcnt(4)" ::: "memory");
        else if (ns < 7)  asm volatile("s_waitcnt vmcnt(6)" ::: "memory");
        else              asm volatile("s_waitcnt vmcnt(2)" ::: "memory");

        const char* bb = smem + 16384 + (ns & 1) * 16384;
        bf16x8 Bf[4];
        #pragma unroll
        for (int kk = 0; kk < 4; ++kk)
            Bf[kk] = *(const bf16x8*)(bb + (wave * 16 + l15) * 256 + ((((kk * 4 + l4) ^ (l15 & 7))) << 4));

        f32x4 acc2[4];
        #pragma unroll
        for (int r = 0; r < 4; ++r) acc2[r] = (f32x4){0.f, 0.f, 0.f, 0.f};
        #pragma unroll
        for (int kk = 0; kk < 4; ++kk)
            #pragma unroll
            for (int r = 0; r < 4; ++r)
                acc2[r] = __builtin_amdgcn_mfma_f32_16x16x32_bf16(A2[r][kk], Bf[kk], acc2[r], 0, 0, 0);

        // epilogue through per-wave LDS patch -> 2 vector stores
        #pragma unroll
        for (int r = 0; r < 4; ++r)
            #pragma unroll
            for (int i = 0; i < 4; ++i)
                *(unsigned short*)(patch + (r * 16 + l4 * 4 + i) * 48 + l15 * 2) = f2bf(acc2[r][i]);
        bf16x8 p0 = *(const bf16x8*)(patch + lane * 48);
        bf16x8 p1 = *(const bf16x8*)(patch + lane * 48 + 16);
        *(bf16x8*)(cw + ns * 128)      = p0;
        *(bf16x8*)(cw + ns * 128 + 16) = p1;
    }
#undef STAGE1
#undef STAGE2
}

// ---------------- combine top-2 ----------------
__global__ __launch_bounds__(256)
void combine_kernel(const unsigned short* __restrict__ contrib, const int* __restrict__ topk_e,
                    const float* __restrict__ topk_w, const float* __restrict__ b2,
                    float* __restrict__ out) {
    int idx = blockIdx.x * 256 + threadIdx.x;
    int row = idx >> 6;
    int cb = (idx & 63) << 3;
    int e0 = topk_e[row * 2], e1 = topk_e[row * 2 + 1];
    float w0 = topk_w[row * 2], w1 = topk_w[row * 2 + 1];
    bf16x8 c0 = *reinterpret_cast<const bf16x8*>(contrib + (size_t)row * 1024 + cb);
    bf16x8 c1 = *reinterpret_cast<const bf16x8*>(contrib + (size_t)row * 1024 + 512 + cb);
    const float* b20 = b2 + e0 * ODIM + cb;
    const float* b21 = b2 + e1 * ODIM + cb;
    float res[8];
    #pragma unroll
    for (int j = 0; j < 8; ++j)
        res[j] = bf2f((unsigned short)c0[j]) + bf2f((unsigned short)c1[j]) + w0 * b20[j] + w1 * b21[j];
    float4 o0 = {res[0], res[1], res[2], res[3]};
    float4 o1 = {res[4], res[5], res[6], res[7]};
    *reinterpret_cast<float4*>(out + (size_t)row * ODIM + cb) = o0;
    *reinterpret_cast<float4*>(out + (size_t)row * ODIM + cb + 4) = o1;
}

extern "C" void kernel_launch(void* const* d_in, const int* in_sizes, int n_in,
                              void* d_out, int out_size, void* d_ws, size_t ws_size,
                              hipStream_t stream) {
    const float* x    = (const float*)d_in[0];
    const float* gW   = (const float*)d_in[1];
    const float* gb   = (const float*)d_in[2];
    const float* W1   = (const float*)d_in[3];
    const float* b1   = (const float*)d_in[4];
    const float* ln_g = (const float*)d_in[5];
    const float* ln_b = (const float*)d_in[6];
    const float* W2   = (const float*)d_in[7];
    const float* b2   = (const float*)d_in[8];
    float* out = (float*)d_out;

    char* ws = (char*)d_ws;
    int*   cnt     = (int*)(ws);
    float* ent_acc = (float*)(ws + 64);
    int*   topk_e  = (int*)(ws + 256);
    float* topk_w  = (float*)(ws + 256 + 131072);
    int*   bucket  = (int*)(ws + 262400);
    unsigned short* xb      = (unsigned short*)(ws + 1310976);   // 16 MB
    unsigned short* w1b     = (unsigned short*)(ws + 18088192);  // 2 MB (blocked W1)
    unsigned short* w2t     = (unsigned short*)(ws + 20185344);  // 2 MB
    unsigned short* contrib = (unsigned short*)(ws + 22282496);  // 32 MB
    // gwT (32 KB f32) aliases the head of contrib: gate reads it before ffn writes contrib
    float* gwT = (float*)(ws + 22282496);

    hipMemsetAsync(ws, 0, 256, stream);

    gwt_prep<<<32, 256, 0, stream>>>(gW, gwT);
    w1_prep<<<dim3(4, 8, NEXP), 256, 0, stream>>>(W1, w1b);
    transpose_to_bf16<<<dim3(ODIM / 32, HDIM / 32, NEXP), dim3(32, 8), 0, stream>>>(W2, w2t, HDIM, ODIM);
    gate_kernel<<<BROWS / 16, 256, 0, stream>>>(x, gwT, gb, cnt, ent_acc, bucket, topk_e, topk_w, xb);
    aux_kernel<<<1, 64, 0, stream>>>(cnt, ent_acc, out + (out_size - 1));
    ffn_kernel<<<NEXP * 64, 256, 0, stream>>>(xb, w1b, w2t, b1, ln_g, ln_b, topk_w, cnt, bucket, contrib);
    combine_kernel<<<(BROWS * ODIM / 8) / 256, 256, 0, stream>>>(contrib, topk_e, topk_w, b2, out);
}

// Round 6
// 114.018 us; speedup vs baseline: 1.3455x; 1.3455x over previous
//
#include <hip/hip_runtime.h>

#define BROWS 16384
#define DDIM  512
#define NEXP  16
#define HDIM  128
#define ODIM  512

typedef __attribute__((ext_vector_type(8))) short bf16x8;
typedef __attribute__((ext_vector_type(4))) float f32x4;

typedef const __attribute__((address_space(1))) unsigned GA;
typedef __attribute__((address_space(3))) unsigned LA;
#define GLD16(g, l) __builtin_amdgcn_global_load_lds((GA*)(g), (LA*)(l), 16, 0, 0)

static __device__ __forceinline__ unsigned short f2bf(float f) {
    union { float f; unsigned u; } v; v.f = f;
    unsigned r = v.u + 0x7fffu + ((v.u >> 16) & 1u);
    return (unsigned short)(r >> 16);
}
static __device__ __forceinline__ float bf2f(unsigned short h) {
    union { unsigned u; float f; } v; v.u = ((unsigned)h) << 16;
    return v.f;
}

// ---------------- gW -> transposed f32 [16][512] ----------------
__global__ __launch_bounds__(256)
void gwt_prep(const float* __restrict__ in, float* __restrict__ out) {
    int i = blockIdx.x * 256 + threadIdx.x;   // 8192 elems
    int d = i >> 4, e = i & 15;
    out[e * 512 + d] = in[i];
}

// ---------------- W1 -> blocked bf16 [e][ks=8][c=128][k=64] ----------------
__global__ __launch_bounds__(256)
void w1_prep(const float* __restrict__ in, unsigned short* __restrict__ out) {
    __shared__ float tile[64][33];
    int e = blockIdx.z;
    int ks = blockIdx.y;
    int cb = blockIdx.x * 32;
    const float* src = in + ((size_t)e * 512 + ks * 64) * 128 + cb;
    int c = threadIdx.x & 31, r8 = threadIdx.x >> 5;
    #pragma unroll
    for (int p = 0; p < 8; ++p)
        tile[p * 8 + r8][c] = src[(size_t)(p * 8 + r8) * 128 + c];
    __syncthreads();
    int k = threadIdx.x & 63, c4 = threadIdx.x >> 6;
    unsigned short* dst = out + (((size_t)e * 8 + ks) * 128 + cb) * 64;
    #pragma unroll
    for (int p = 0; p < 8; ++p)
        dst[(size_t)(c4 + p * 4) * 64 + k] = f2bf(tile[k][c4 + p * 4]);
}

// ---------------- transpose W2 to bf16 [e][O][H] ----------------
__global__ __launch_bounds__(256)
void transpose_to_bf16(const float* __restrict__ in, unsigned short* __restrict__ out, int R, int C) {
    __shared__ float tile[32][33];
    int e = blockIdx.z;
    in  += (size_t)e * R * C;
    out += (size_t)e * R * C;
    int c0 = blockIdx.x * 32, r0 = blockIdx.y * 32;
    for (int i = threadIdx.y; i < 32; i += 8)
        tile[i][threadIdx.x] = in[(size_t)(r0 + i) * C + c0 + threadIdx.x];
    __syncthreads();
    for (int i = threadIdx.y; i < 32; i += 8)
        out[(size_t)(c0 + i) * R + r0 + threadIdx.x] = f2bf(tile[threadIdx.x][i]);
}

// ---------------- gating (fused with x->bf16 conversion) ----------------
// 1024 blocks x 256 threads; 16 rows/block, 4 rows/wave, 2 rows/lane.
// gwT staged LDS via COALESCED float4 loads from pre-transposed global copy.
__global__ __launch_bounds__(256)
void gate_kernel(const float* __restrict__ x, const float* __restrict__ gwTg,
                 const float* __restrict__ gb,
                 int* cnt, float* ent_acc, int* bucket, int* topk_e, float* topk_w,
                 unsigned short* __restrict__ xb) {
    __shared__ __align__(16) float gwT[16 * 512];   // [e][d], 32 KB
    __shared__ int lcnt[16];
    __shared__ int gbase[16];
    __shared__ int entpack[32];
    __shared__ float entf;

    int tid = threadIdx.x;
    int wave = tid >> 6, lane = tid & 63;
    int ds = lane & 31, rg = lane >> 5;
    int wrow = blockIdx.x * 16 + wave * 4 + rg * 2;   // rows: wrow, wrow+1

    // issue per-lane x loads (8 independent 16B loads in flight)
    float4 xv[2][4];
    #pragma unroll
    for (int rr = 0; rr < 2; ++rr)
        #pragma unroll
        for (int di = 0; di < 4; ++di)
            xv[rr][di] = *reinterpret_cast<const float4*>(x + (size_t)(wrow + rr) * DDIM + ds * 4 + di * 128);

    // stage gwT: 8 coalesced float4 per thread (32 KB total)
    {
        const float4* src = reinterpret_cast<const float4*>(gwTg);
        float4* dst = reinterpret_cast<float4*>(gwT);
        #pragma unroll
        for (int k = 0; k < 8; ++k)
            dst[tid + k * 256] = src[tid + k * 256];
    }
    if (tid < 16) lcnt[tid] = 0;
    if (tid == 0) entf = 0.f;

    // fused x -> bf16 write
    #pragma unroll
    for (int rr = 0; rr < 2; ++rr)
        #pragma unroll
        for (int di = 0; di < 4; ++di) {
            uint2 p;
            p.x = (unsigned)f2bf(xv[rr][di].x) | ((unsigned)f2bf(xv[rr][di].y) << 16);
            p.y = (unsigned)f2bf(xv[rr][di].z) | ((unsigned)f2bf(xv[rr][di].w) << 16);
            *reinterpret_cast<uint2*>(xb + (size_t)(wrow + rr) * DDIM + ds * 4 + di * 128) = p;
        }
    __syncthreads();

    float acc[2][16];
    #pragma unroll
    for (int rr = 0; rr < 2; ++rr)
        #pragma unroll
        for (int e = 0; e < 16; ++e) acc[rr][e] = 0.f;

    const float4* gw4 = reinterpret_cast<const float4*>(gwT);
    #pragma unroll
    for (int di = 0; di < 4; ++di) {
        #pragma unroll
        for (int e = 0; e < 16; ++e) {
            float4 g = gw4[e * 128 + ds + di * 32];
            #pragma unroll
            for (int rr = 0; rr < 2; ++rr) {
                acc[rr][e] = fmaf(xv[rr][di].x, g.x, acc[rr][e]);
                acc[rr][e] = fmaf(xv[rr][di].y, g.y, acc[rr][e]);
                acc[rr][e] = fmaf(xv[rr][di].z, g.z, acc[rr][e]);
                acc[rr][e] = fmaf(xv[rr][di].w, g.w, acc[rr][e]);
            }
        }
    }

    // butterfly reduce across the 32 d-slice lanes; all lanes get sums
    #pragma unroll
    for (int rr = 0; rr < 2; ++rr)
        #pragma unroll
        for (int e = 0; e < 16; ++e) {
            float v = acc[rr][e];
            v += __shfl_xor(v, 1);  v += __shfl_xor(v, 2);
            v += __shfl_xor(v, 4);  v += __shfl_xor(v, 8);
            v += __shfl_xor(v, 16);
            acc[rr][e] = v;
        }

    if (ds < 2) {
        int rr = ds;
        int row = wrow + rr;
        float sc[16];
        #pragma unroll
        for (int e = 0; e < 16; ++e) sc[e] = acc[rr][e] + gb[e];
        float v0 = -1e30f, v1 = -1e30f; int i0 = 0, i1 = 0;
        #pragma unroll
        for (int k = 0; k < 16; ++k) {
            float sv = sc[k];
            if (sv > v0) { v1 = v0; i1 = i0; v0 = sv; i0 = k; }
            else if (sv > v1) { v1 = sv; i1 = k; }
        }
        float Z = 0.f, S1 = 0.f;
        #pragma unroll
        for (int k = 0; k < 16; ++k) {
            float t = sc[k] - v0;
            float ex = expf(t);
            Z += ex; S1 = fmaf(ex, t, S1);
        }
        float entloc = logf(Z) - S1 / Z;
        float w0 = 1.0f / (1.0f + expf(v1 - v0));
        topk_e[row * 2]     = i0;
        topk_e[row * 2 + 1] = i1;
        topk_w[row * 2]     = w0;
        topk_w[row * 2 + 1] = 1.0f - w0;
        int ib = wave * 4 + rg * 2 + rr;   // [0,16)
        int lp0 = atomicAdd(&lcnt[i0], 1);
        entpack[ib * 2]     = (row << 1) | (i0 << 15) | (lp0 << 19);
        int lp1 = atomicAdd(&lcnt[i1], 1);
        entpack[ib * 2 + 1] = ((row << 1) | 1) | (i1 << 15) | (lp1 << 19);
        atomicAdd(&entf, entloc);
    }
    __syncthreads();
    if (tid < 16) gbase[tid] = atomicAdd(&cnt[tid], lcnt[tid]);
    if (tid == 0) atomicAdd(ent_acc, entf);
    __syncthreads();
    if (tid < 32) {
        int p = entpack[tid];
        int rowslot = p & 0x7FFF;
        int e = (p >> 15) & 15;
        int lpos = p >> 19;
        bucket[e * BROWS + gbase[e] + lpos] = rowslot;
    }
}

// ---------------- aux loss ----------------
__global__ void aux_kernel(const int* __restrict__ cnt, const float* __restrict__ ent_acc,
                           float* __restrict__ outp) {
    if (threadIdx.x == 0 && blockIdx.x == 0) {
        float lb = 0.f;
        for (int k = 0; k < 16; ++k) {
            float u = (float)cnt[k] * (1.f / 16384.f) - 0.0625f;
            lb += u * u;
        }
        lb *= (1.f / 16.f);
        float ment = ent_acc[0] * (1.f / 16384.f);
        outp[0] = lb - 0.1f * ment;
    }
}

// ---------------- grouped sparse FFN, pipelined ----------------
__global__ __launch_bounds__(256, 2)
void ffn_kernel(const unsigned short* __restrict__ xb,
                const unsigned short* __restrict__ w1b,   // [E][8][128][64] bf16
                const unsigned short* __restrict__ w2t,   // [E][O][H] bf16
                const float* __restrict__ b1, const float* __restrict__ ln_g,
                const float* __restrict__ ln_b, const float* __restrict__ topk_w,
                const int* __restrict__ cnt, const int* __restrict__ bucket,
                unsigned short* __restrict__ contrib) {
    int e = blockIdx.x >> 6;
    int t = blockIdx.x & 63;
    int n = cnt[e];
    int base = t * 64;
    if (base >= n) return;
    int rows = n - base; if (rows > 64) rows = 64;

    __shared__ __align__(16) char smem[51712];

    const int tid = threadIdx.x;
    const int wave = tid >> 6, lane = tid & 63;
    const int l15 = lane & 15, l4 = lane >> 4;
    const int bbase = e * BROWS + base;

    if (tid < 64) {
        int idx = tid < rows ? tid : (rows - 1);
        int rs = bucket[bbase + idx];
        *(int*)(smem + 51200 + tid * 4) = rs;
        *(float*)(smem + 51456 + tid * 4) = topk_w[rs];
    }

    const int lsw = (((lane & 7) ^ ((lane >> 3) & 7)) << 4);
    int ar0 = wave * 16 + (lane >> 3);
    int ar1 = ar0 + 8;
    size_t grow0 = (size_t)(bucket[bbase + (ar0 < rows ? ar0 : rows - 1)] >> 1) * 1024;
    size_t grow1 = (size_t)(bucket[bbase + (ar1 < rows ? ar1 : rows - 1)] >> 1) * 1024;
    const char* xbp = (const char*)xb;
    const char* w1e = (const char*)w1b + (size_t)e * 131072;
    const char* w2e = (const char*)w2t + (size_t)e * 131072;
    const int sw2e = (((lane & 15) ^ (lane >> 4)) << 4);
    const int sw2o = sw2e ^ 64;

#define STAGE1(ks_, buf_) do { \
    char* ab_ = smem + (buf_) * 8192; \
    char* bb_ = smem + 16384 + (buf_) * 16384; \
    GLD16(xbp + grow0 + (ks_) * 128 + lsw, ab_ + (wave * 2 + 0) * 1024); \
    GLD16(xbp + grow1 + (ks_) * 128 + lsw, ab_ + (wave * 2 + 1) * 1024); \
    const char* s1_ = w1e + (ks_) * 16384 + ((lane >> 3) << 7) + lsw; \
    GLD16(s1_ + (wave * 4 + 0) * 1024, bb_ + (wave * 4 + 0) * 1024); \
    GLD16(s1_ + (wave * 4 + 1) * 1024, bb_ + (wave * 4 + 1) * 1024); \
    GLD16(s1_ + (wave * 4 + 2) * 1024, bb_ + (wave * 4 + 2) * 1024); \
    GLD16(s1_ + (wave * 4 + 3) * 1024, bb_ + (wave * 4 + 3) * 1024); \
} while (0)

#define STAGE2(ns_, buf_) do { \
    char* bb_ = smem + 16384 + (buf_) * 16384; \
    const char* s2_ = w2e + (size_t)(ns_) * 16384 + ((lane >> 4) << 8); \
    GLD16(s2_ + (wave * 4 + 0) * 1024 + sw2e, bb_ + (wave * 4 + 0) * 1024); \
    GLD16(s2_ + (wave * 4 + 1) * 1024 + sw2o, bb_ + (wave * 4 + 1) * 1024); \
    GLD16(s2_ + (wave * 4 + 2) * 1024 + sw2e, bb_ + (wave * 4 + 2) * 1024); \
    GLD16(s2_ + (wave * 4 + 3) * 1024 + sw2o, bb_ + (wave * 4 + 3) * 1024); \
} while (0)

    // ================= GEMM1: h = x_tile @ W1[e] =================
    STAGE1(0, 0);
    f32x4 acc1[4][2];
    #pragma unroll
    for (int r = 0; r < 4; ++r)
        #pragma unroll
        for (int c = 0; c < 2; ++c)
            acc1[r][c] = (f32x4){0.f, 0.f, 0.f, 0.f};

    #pragma unroll
    for (int ks = 0; ks < 8; ++ks) {
        const int cur = ks & 1;
        if (ks < 7) {
            STAGE1(ks + 1, cur ^ 1);
            asm volatile("s_waitcnt vmcnt(6)" ::: "memory");
        } else {
            asm volatile("s_waitcnt vmcnt(0)" ::: "memory");
        }
        asm volatile("s_barrier" ::: "memory");
        const char* ab = smem + cur * 8192;
        const char* bb = smem + 16384 + cur * 16384;
        #pragma unroll
        for (int ks2 = 0; ks2 < 2; ++ks2) {
            const int cb = (((ks2 * 4 + l4) ^ (l15 & 7)) << 4);
            bf16x8 a[4], bg[2];
            #pragma unroll
            for (int r = 0; r < 4; ++r)
                a[r] = *(const bf16x8*)(ab + (r * 16 + l15) * 128 + cb);
            bg[0] = *(const bf16x8*)(bb + (wave * 32 + l15) * 128 + cb);
            bg[1] = *(const bf16x8*)(bb + (wave * 32 + 16 + l15) * 128 + cb);
            #pragma unroll
            for (int r = 0; r < 4; ++r) {
                acc1[r][0] = __builtin_amdgcn_mfma_f32_16x16x32_bf16(a[r], bg[0], acc1[r][0], 0, 0, 0);
                acc1[r][1] = __builtin_amdgcn_mfma_f32_16x16x32_bf16(a[r], bg[1], acc1[r][1], 0, 0, 0);
            }
        }
        asm volatile("s_waitcnt lgkmcnt(0)\n\ts_barrier" ::: "memory");
    }

    // kick off first W2 slice while we do GELU/LN
    STAGE2(0, 0);

    // ================= bias + exact GELU (in regs) + LN partials =================
    const float* b1e = b1 + e * HDIM;
    const int c0 = wave * 32 + l15, c1 = c0 + 16;
    float bias0 = b1e[c0], bias1 = b1e[c1];
    #pragma unroll
    for (int r = 0; r < 4; ++r)
        #pragma unroll
        for (int i = 0; i < 4; ++i) {
            int row = r * 16 + l4 * 4 + i;
            float v0 = acc1[r][0][i] + bias0;
            float v1 = acc1[r][1][i] + bias1;
            v0 = 0.5f * v0 * (1.0f + erff(v0 * 0.70710678f));
            v1 = 0.5f * v1 * (1.0f + erff(v1 * 0.70710678f));
            acc1[r][0][i] = v0; acc1[r][1][i] = v1;
            float s = v0 + v1, ss = v0 * v0 + v1 * v1;
            s  += __shfl_xor(s, 1);  s  += __shfl_xor(s, 2);
            s  += __shfl_xor(s, 4);  s  += __shfl_xor(s, 8);
            ss += __shfl_xor(ss, 1); ss += __shfl_xor(ss, 2);
            ss += __shfl_xor(ss, 4); ss += __shfl_xor(ss, 8);
            if (l15 == 0) {
                *(float*)(smem + 49152 + row * 32 + wave * 8)     = s;
                *(float*)(smem + 49152 + row * 32 + wave * 8 + 4) = ss;
            }
        }
    asm volatile("s_waitcnt lgkmcnt(0)\n\ts_barrier" ::: "memory");

    // ================= LN apply (gate weight folded in) -> h_ln bf16 swizzled =================
    {
        const float* lge = ln_g + e * HDIM;
        const float* lbe = ln_b + e * HDIM;
        float g0 = lge[c0], g1 = lge[c1], be0 = lbe[c0], be1 = lbe[c1];
        #pragma unroll
        for (int r = 0; r < 4; ++r)
            #pragma unroll
            for (int i = 0; i < 4; ++i) {
                int row = r * 16 + l4 * 4 + i;
                float4 p0 = *(const float4*)(smem + 49152 + row * 32);
                float4 p1 = *(const float4*)(smem + 49152 + row * 32 + 16);
                float s  = p0.x + p0.z + p1.x + p1.z;
                float ss = p0.y + p0.w + p1.y + p1.w;
                float mean = s * 0.0078125f;
                float var  = fmaf(-mean, mean, ss * 0.0078125f);
                float rstd = rsqrtf(var + 1e-5f);
                float w = *(const float*)(smem + 51456 + row * 4);
                float h0 = ((acc1[r][0][i] - mean) * rstd * g0 + be0) * w;
                float h1 = ((acc1[r][1][i] - mean) * rstd * g1 + be1) * w;
                int wr = (row & 7) << 4;
                *(unsigned short*)(smem + row * 256 + ((c0 * 2) ^ wr)) = f2bf(h0);
                *(unsigned short*)(smem + row * 256 + ((c1 * 2) ^ wr)) = f2bf(h1);
            }
    }
    asm volatile("s_waitcnt lgkmcnt(0)\n\ts_barrier" ::: "memory");

    // ================= hoist GEMM2 A fragments to registers =================
    bf16x8 A2[4][4];
    #pragma unroll
    for (int r = 0; r < 4; ++r)
        #pragma unroll
        for (int kk = 0; kk < 4; ++kk)
            A2[r][kk] = *(const bf16x8*)(smem + (r * 16 + l15) * 256 + ((((kk * 4 + l4) ^ (l15 & 7))) << 4));
    asm volatile("s_waitcnt lgkmcnt(0)\n\ts_barrier" ::: "memory");   // h_ln region now reusable as patches

    // ================= GEMM2: contrib = h_ln @ W2[e], barrier-free =================
    STAGE2(1, 1);
    char* patch = smem + wave * 3072;   // 64 rows x 48B (16 cols bf16 + pad)
    const int rsoff = (*(const int*)(smem + 51200 + lane * 4)) << 10;
    char* cw = (char*)contrib + rsoff + wave * 32;

    #pragma unroll
    for (int ns = 0; ns < 8; ++ns) {
        if (ns < 7) {
            asm volatile("s_waitcnt lgkmcnt(0)" ::: "memory");
            if (ns > 0) STAGE2(ns + 1, (ns + 1) & 1);
        }
        if (ns == 0)      asm volatile("s_waitcnt vmcnt(4)" ::: "memory");
        else if (ns < 7)  asm volatile("s_waitcnt vmcnt(6)" ::: "memory");
        else              asm volatile("s_waitcnt vmcnt(2)" ::: "memory");

        const char* bb = smem + 16384 + (ns & 1) * 16384;
        bf16x8 Bf[4];
        #pragma unroll
        for (int kk = 0; kk < 4; ++kk)
            Bf[kk] = *(const bf16x8*)(bb + (wave * 16 + l15) * 256 + ((((kk * 4 + l4) ^ (l15 & 7))) << 4));

        f32x4 acc2[4];
        #pragma unroll
        for (int r = 0; r < 4; ++r) acc2[r] = (f32x4){0.f, 0.f, 0.f, 0.f};
        #pragma unroll
        for (int kk = 0; kk < 4; ++kk)
            #pragma unroll
            for (int r = 0; r < 4; ++r)
                acc2[r] = __builtin_amdgcn_mfma_f32_16x16x32_bf16(A2[r][kk], Bf[kk], acc2[r], 0, 0, 0);

        // epilogue through per-wave LDS patch -> 2 vector stores
        #pragma unroll
        for (int r = 0; r < 4; ++r)
            #pragma unroll
            for (int i = 0; i < 4; ++i)
                *(unsigned short*)(patch + (r * 16 + l4 * 4 + i) * 48 + l15 * 2) = f2bf(acc2[r][i]);
        bf16x8 p0 = *(const bf16x8*)(patch + lane * 48);
        bf16x8 p1 = *(const bf16x8*)(patch + lane * 48 + 16);
        *(bf16x8*)(cw + ns * 128)      = p0;
        *(bf16x8*)(cw + ns * 128 + 16) = p1;
    }
#undef STAGE1
#undef STAGE2
}

// ---------------- combine top-2 ----------------
__global__ __launch_bounds__(256)
void combine_kernel(const unsigned short* __restrict__ contrib, const int* __restrict__ topk_e,
                    const float* __restrict__ topk_w, const float* __restrict__ b2,
                    float* __restrict__ out) {
    int idx = blockIdx.x * 256 + threadIdx.x;
    int row = idx >> 6;
    int cb = (idx & 63) << 3;
    int e0 = topk_e[row * 2], e1 = topk_e[row * 2 + 1];
    float w0 = topk_w[row * 2], w1 = topk_w[row * 2 + 1];
    bf16x8 c0 = *reinterpret_cast<const bf16x8*>(contrib + (size_t)row * 1024 + cb);
    bf16x8 c1 = *reinterpret_cast<const bf16x8*>(contrib + (size_t)row * 1024 + 512 + cb);
    const float* b20 = b2 + e0 * ODIM + cb;
    const float* b21 = b2 + e1 * ODIM + cb;
    float res[8];
    #pragma unroll
    for (int j = 0; j < 8; ++j)
        res[j] = bf2f((unsigned short)c0[j]) + bf2f((unsigned short)c1[j]) + w0 * b20[j] + w1 * b21[j];
    float4 o0 = {res[0], res[1], res[2], res[3]};
    float4 o1 = {res[4], res[5], res[6], res[7]};
    *reinterpret_cast<float4*>(out + (size_t)row * ODIM + cb) = o0;
    *reinterpret_cast<float4*>(out + (size_t)row * ODIM + cb + 4) = o1;
}

extern "C" void kernel_launch(void* const* d_in, const int* in_sizes, int n_in,
                              void* d_out, int out_size, void* d_ws, size_t ws_size,
                              hipStream_t stream) {
    const float* x    = (const float*)d_in[0];
    const float* gW   = (const float*)d_in[1];
    const float* gb   = (const float*)d_in[2];
    const float* W1   = (const float*)d_in[3];
    const float* b1   = (const float*)d_in[4];
    const float* ln_g = (const float*)d_in[5];
    const float* ln_b = (const float*)d_in[6];
    const float* W2   = (const float*)d_in[7];
    const float* b2   = (const float*)d_in[8];
    float* out = (float*)d_out;

    char* ws = (char*)d_ws;
    int*   cnt     = (int*)(ws);
    float* ent_acc = (float*)(ws + 64);
    int*   topk_e  = (int*)(ws + 256);
    float* topk_w  = (float*)(ws + 256 + 131072);
    int*   bucket  = (int*)(ws + 262400);
    unsigned short* xb      = (unsigned short*)(ws + 1310976);   // 16 MB
    unsigned short* w1b     = (unsigned short*)(ws + 18088192);  // 2 MB (blocked W1)
    unsigned short* w2t     = (unsigned short*)(ws + 20185344);  // 2 MB
    unsigned short* contrib = (unsigned short*)(ws + 22282496);  // 32 MB
    // gwT (32 KB f32) aliases the head of contrib: gate reads it before ffn writes contrib
    float* gwT = (float*)(ws + 22282496);

    hipMemsetAsync(ws, 0, 256, stream);

    gwt_prep<<<32, 256, 0, stream>>>(gW, gwT);
    w1_prep<<<dim3(4, 8, NEXP), 256, 0, stream>>>(W1, w1b);
    transpose_to_bf16<<<dim3(ODIM / 32, HDIM / 32, NEXP), dim3(32, 8), 0, stream>>>(W2, w2t, HDIM, ODIM);
    gate_kernel<<<BROWS / 16, 256, 0, stream>>>(x, gwT, gb, cnt, ent_acc, bucket, topk_e, topk_w, xb);
    aux_kernel<<<1, 64, 0, stream>>>(cnt, ent_acc, out + (out_size - 1));
    ffn_kernel<<<NEXP * 64, 256, 0, stream>>>(xb, w1b, w2t, b1, ln_g, ln_b, topk_w, cnt, bucket, contrib);
    combine_kernel<<<(BROWS * ODIM / 8) / 256, 256, 0, stream>>>(contrib, topk_e, topk_w, b2, out);
}

// Round 7
// 108.684 us; speedup vs baseline: 1.4115x; 1.0491x over previous
//
#include <hip/hip_runtime.h>

#define BROWS 16384
#define DDIM  512
#define NEXP  16
#define HDIM  128
#define ODIM  512
#define MAXTILES 528

typedef __attribute__((ext_vector_type(8))) short bf16x8;
typedef __attribute__((ext_vector_type(4))) float f32x4;

typedef const __attribute__((address_space(1))) unsigned GA;
typedef __attribute__((address_space(3))) unsigned LA;
#define GLD16(g, l) __builtin_amdgcn_global_load_lds((GA*)(g), (LA*)(l), 16, 0, 0)

static __device__ __forceinline__ unsigned short f2bf(float f) {
    union { float f; unsigned u; } v; v.f = f;
    unsigned r = v.u + 0x7fffu + ((v.u >> 16) & 1u);
    return (unsigned short)(r >> 16);
}
static __device__ __forceinline__ float bf2f(unsigned short h) {
    union { unsigned u; float f; } v; v.u = ((unsigned)h) << 16;
    return v.f;
}

// ---------------- gW -> transposed f32 [16][512] ----------------
__global__ __launch_bounds__(256)
void gwt_prep(const float* __restrict__ in, float* __restrict__ out) {
    int i = blockIdx.x * 256 + threadIdx.x;   // 8192 elems
    int d = i >> 4, e = i & 15;
    out[e * 512 + d] = in[i];
}

// ---------------- W1 -> blocked bf16 [e][ks=8][c=128][k=64] ----------------
__global__ __launch_bounds__(256)
void w1_prep(const float* __restrict__ in, unsigned short* __restrict__ out) {
    __shared__ float tile[64][33];
    int e = blockIdx.z;
    int ks = blockIdx.y;
    int cb = blockIdx.x * 32;
    const float* src = in + ((size_t)e * 512 + ks * 64) * 128 + cb;
    int c = threadIdx.x & 31, r8 = threadIdx.x >> 5;
    #pragma unroll
    for (int p = 0; p < 8; ++p)
        tile[p * 8 + r8][c] = src[(size_t)(p * 8 + r8) * 128 + c];
    __syncthreads();
    int k = threadIdx.x & 63, c4 = threadIdx.x >> 6;
    unsigned short* dst = out + (((size_t)e * 8 + ks) * 128 + cb) * 64;
    #pragma unroll
    for (int p = 0; p < 8; ++p)
        dst[(size_t)(c4 + p * 4) * 64 + k] = f2bf(tile[k][c4 + p * 4]);
}

// ---------------- transpose W2 to bf16 [e][O][H] ----------------
__global__ __launch_bounds__(256)
void transpose_to_bf16(const float* __restrict__ in, unsigned short* __restrict__ out, int R, int C) {
    __shared__ float tile[32][33];
    int e = blockIdx.z;
    in  += (size_t)e * R * C;
    out += (size_t)e * R * C;
    int c0 = blockIdx.x * 32, r0 = blockIdx.y * 32;
    for (int i = threadIdx.y; i < 32; i += 8)
        tile[i][threadIdx.x] = in[(size_t)(r0 + i) * C + c0 + threadIdx.x];
    __syncthreads();
    for (int i = threadIdx.y; i < 32; i += 8)
        out[(size_t)(c0 + i) * R + r0 + threadIdx.x] = f2bf(tile[threadIdx.x][i]);
}

// ---------------- gating (fused with x->bf16 conversion) ----------------
__global__ __launch_bounds__(256)
void gate_kernel(const float* __restrict__ x, const float* __restrict__ gwTg,
                 const float* __restrict__ gb,
                 int* cnt, float* ent_acc, int* bucket, int* topk_e, float* topk_w,
                 unsigned short* __restrict__ xb) {
    __shared__ __align__(16) float gwT[16 * 512];   // [e][d], 32 KB
    __shared__ int lcnt[16];
    __shared__ int gbase[16];
    __shared__ int entpack[32];
    __shared__ float entf;

    int tid = threadIdx.x;
    int wave = tid >> 6, lane = tid & 63;
    int ds = lane & 31, rg = lane >> 5;
    int wrow = blockIdx.x * 16 + wave * 4 + rg * 2;   // rows: wrow, wrow+1

    // issue per-lane x loads (8 independent 16B loads in flight)
    float4 xv[2][4];
    #pragma unroll
    for (int rr = 0; rr < 2; ++rr)
        #pragma unroll
        for (int di = 0; di < 4; ++di)
            xv[rr][di] = *reinterpret_cast<const float4*>(x + (size_t)(wrow + rr) * DDIM + ds * 4 + di * 128);

    // stage gwT: 8 coalesced float4 per thread (32 KB total)
    {
        const float4* src = reinterpret_cast<const float4*>(gwTg);
        float4* dst = reinterpret_cast<float4*>(gwT);
        #pragma unroll
        for (int k = 0; k < 8; ++k)
            dst[tid + k * 256] = src[tid + k * 256];
    }
    if (tid < 16) lcnt[tid] = 0;
    if (tid == 0) entf = 0.f;

    // fused x -> bf16 write
    #pragma unroll
    for (int rr = 0; rr < 2; ++rr)
        #pragma unroll
        for (int di = 0; di < 4; ++di) {
            uint2 p;
            p.x = (unsigned)f2bf(xv[rr][di].x) | ((unsigned)f2bf(xv[rr][di].y) << 16);
            p.y = (unsigned)f2bf(xv[rr][di].z) | ((unsigned)f2bf(xv[rr][di].w) << 16);
            *reinterpret_cast<uint2*>(xb + (size_t)(wrow + rr) * DDIM + ds * 4 + di * 128) = p;
        }
    __syncthreads();

    float acc[2][16];
    #pragma unroll
    for (int rr = 0; rr < 2; ++rr)
        #pragma unroll
        for (int e = 0; e < 16; ++e) acc[rr][e] = 0.f;

    const float4* gw4 = reinterpret_cast<const float4*>(gwT);
    #pragma unroll
    for (int di = 0; di < 4; ++di) {
        #pragma unroll
        for (int e = 0; e < 16; ++e) {
            float4 g = gw4[e * 128 + ds + di * 32];
            #pragma unroll
            for (int rr = 0; rr < 2; ++rr) {
                acc[rr][e] = fmaf(xv[rr][di].x, g.x, acc[rr][e]);
                acc[rr][e] = fmaf(xv[rr][di].y, g.y, acc[rr][e]);
                acc[rr][e] = fmaf(xv[rr][di].z, g.z, acc[rr][e]);
                acc[rr][e] = fmaf(xv[rr][di].w, g.w, acc[rr][e]);
            }
        }
    }

    // butterfly reduce across the 32 d-slice lanes; all lanes get sums
    #pragma unroll
    for (int rr = 0; rr < 2; ++rr)
        #pragma unroll
        for (int e = 0; e < 16; ++e) {
            float v = acc[rr][e];
            v += __shfl_xor(v, 1);  v += __shfl_xor(v, 2);
            v += __shfl_xor(v, 4);  v += __shfl_xor(v, 8);
            v += __shfl_xor(v, 16);
            acc[rr][e] = v;
        }

    if (ds < 2) {
        int rr = ds;
        int row = wrow + rr;
        float sc[16];
        #pragma unroll
        for (int e = 0; e < 16; ++e) sc[e] = acc[rr][e] + gb[e];
        float v0 = -1e30f, v1 = -1e30f; int i0 = 0, i1 = 0;
        #pragma unroll
        for (int k = 0; k < 16; ++k) {
            float sv = sc[k];
            if (sv > v0) { v1 = v0; i1 = i0; v0 = sv; i0 = k; }
            else if (sv > v1) { v1 = sv; i1 = k; }
        }
        float Z = 0.f, S1 = 0.f;
        #pragma unroll
        for (int k = 0; k < 16; ++k) {
            float t = sc[k] - v0;
            float ex = expf(t);
            Z += ex; S1 = fmaf(ex, t, S1);
        }
        float entloc = logf(Z) - S1 / Z;
        float w0 = 1.0f / (1.0f + expf(v1 - v0));
        topk_e[row * 2]     = i0;
        topk_e[row * 2 + 1] = i1;
        topk_w[row * 2]     = w0;
        topk_w[row * 2 + 1] = 1.0f - w0;
        int ib = wave * 4 + rg * 2 + rr;   // [0,16)
        int lp0 = atomicAdd(&lcnt[i0], 1);
        entpack[ib * 2]     = (row << 1) | (i0 << 15) | (lp0 << 19);
        int lp1 = atomicAdd(&lcnt[i1], 1);
        entpack[ib * 2 + 1] = ((row << 1) | 1) | (i1 << 15) | (lp1 << 19);
        atomicAdd(&entf, entloc);
    }
    __syncthreads();
    if (tid < 16) gbase[tid] = atomicAdd(&cnt[tid], lcnt[tid]);
    if (tid == 0) atomicAdd(ent_acc, entf);
    __syncthreads();
    if (tid < 32) {
        int p = entpack[tid];
        int rowslot = p & 0x7FFF;
        int e = (p >> 15) & 15;
        int lpos = p >> 19;
        bucket[e * BROWS + gbase[e] + lpos] = rowslot;
    }
}

// ---------------- aux loss + dense tile table ----------------
__global__ void aux_kernel(const int* __restrict__ cnt, const float* __restrict__ ent_acc,
                           float* __restrict__ outp, int* __restrict__ tiledesc) {
    __shared__ int off[17];
    int tid = threadIdx.x;
    if (tid == 0) {
        float lb = 0.f;
        for (int k = 0; k < 16; ++k) {
            float u = (float)cnt[k] * (1.f / 16384.f) - 0.0625f;
            lb += u * u;
        }
        lb *= (1.f / 16.f);
        float ment = ent_acc[0] * (1.f / 16384.f);
        outp[0] = lb - 0.1f * ment;
        int o = 0;
        for (int e = 0; e < 16; ++e) { off[e] = o; o += (cnt[e] + 63) >> 6; }
        off[16] = o;
    }
    __syncthreads();
    #pragma unroll 1
    for (int e = 0; e < 16; ++e) {
        int nt = off[e + 1] - off[e];
        for (int i = tid; i < nt; i += 64)
            tiledesc[off[e] + i] = e | (i << 8);
    }
    for (int i = off[16] + tid; i < MAXTILES; i += 64)
        tiledesc[i] = -1;
}

// ---------------- grouped sparse FFN, pipelined, dense tile grid ----------------
__global__ __launch_bounds__(256, 2)
void ffn_kernel(const unsigned short* __restrict__ xb,
                const unsigned short* __restrict__ w1b,   // [E][8][128][64] bf16
                const unsigned short* __restrict__ w2t,   // [E][O][H] bf16
                const float* __restrict__ b1, const float* __restrict__ ln_g,
                const float* __restrict__ ln_b, const float* __restrict__ topk_w,
                const int* __restrict__ cnt, const int* __restrict__ bucket,
                const int* __restrict__ tiledesc,
                unsigned short* __restrict__ contrib) {
    int d = tiledesc[blockIdx.x];
    if (d < 0) return;
    int e = d & 255;
    int t = d >> 8;
    int n = cnt[e];
    int base = t * 64;
    int rows = n - base; if (rows > 64) rows = 64;

    __shared__ __align__(16) char smem[51712];

    const int tid = threadIdx.x;
    const int wave = tid >> 6, lane = tid & 63;
    const int l15 = lane & 15, l4 = lane >> 4;
    const int bbase = e * BROWS + base;

    if (tid < 64) {
        int idx = tid < rows ? tid : (rows - 1);
        int rs = bucket[bbase + idx];
        *(int*)(smem + 51200 + tid * 4) = rs;
        *(float*)(smem + 51456 + tid * 4) = topk_w[rs];
    }

    const int lsw = (((lane & 7) ^ ((lane >> 3) & 7)) << 4);
    int ar0 = wave * 16 + (lane >> 3);
    int ar1 = ar0 + 8;
    size_t grow0 = (size_t)(bucket[bbase + (ar0 < rows ? ar0 : rows - 1)] >> 1) * 1024;
    size_t grow1 = (size_t)(bucket[bbase + (ar1 < rows ? ar1 : rows - 1)] >> 1) * 1024;
    const char* xbp = (const char*)xb;
    const char* w1e = (const char*)w1b + (size_t)e * 131072;
    const char* w2e = (const char*)w2t + (size_t)e * 131072;
    const int sw2e = (((lane & 15) ^ (lane >> 4)) << 4);
    const int sw2o = sw2e ^ 64;

#define STAGE1(ks_, buf_) do { \
    char* ab_ = smem + (buf_) * 8192; \
    char* bb_ = smem + 16384 + (buf_) * 16384; \
    GLD16(xbp + grow0 + (ks_) * 128 + lsw, ab_ + (wave * 2 + 0) * 1024); \
    GLD16(xbp + grow1 + (ks_) * 128 + lsw, ab_ + (wave * 2 + 1) * 1024); \
    const char* s1_ = w1e + (ks_) * 16384 + ((lane >> 3) << 7) + lsw; \
    GLD16(s1_ + (wave * 4 + 0) * 1024, bb_ + (wave * 4 + 0) * 1024); \
    GLD16(s1_ + (wave * 4 + 1) * 1024, bb_ + (wave * 4 + 1) * 1024); \
    GLD16(s1_ + (wave * 4 + 2) * 1024, bb_ + (wave * 4 + 2) * 1024); \
    GLD16(s1_ + (wave * 4 + 3) * 1024, bb_ + (wave * 4 + 3) * 1024); \
} while (0)

#define STAGE2(ns_, buf_) do { \
    char* bb_ = smem + 16384 + (buf_) * 16384; \
    const char* s2_ = w2e + (size_t)(ns_) * 16384 + ((lane >> 4) << 8); \
    GLD16(s2_ + (wave * 4 + 0) * 1024 + sw2e, bb_ + (wave * 4 + 0) * 1024); \
    GLD16(s2_ + (wave * 4 + 1) * 1024 + sw2o, bb_ + (wave * 4 + 1) * 1024); \
    GLD16(s2_ + (wave * 4 + 2) * 1024 + sw2e, bb_ + (wave * 4 + 2) * 1024); \
    GLD16(s2_ + (wave * 4 + 3) * 1024 + sw2o, bb_ + (wave * 4 + 3) * 1024); \
} while (0)

    // ================= GEMM1: h = x_tile @ W1[e] =================
    STAGE1(0, 0);
    f32x4 acc1[4][2];
    #pragma unroll
    for (int r = 0; r < 4; ++r)
        #pragma unroll
        for (int c = 0; c < 2; ++c)
            acc1[r][c] = (f32x4){0.f, 0.f, 0.f, 0.f};

    #pragma unroll
    for (int ks = 0; ks < 8; ++ks) {
        const int cur = ks & 1;
        if (ks < 7) {
            STAGE1(ks + 1, cur ^ 1);
            asm volatile("s_waitcnt vmcnt(6)" ::: "memory");
        } else {
            asm volatile("s_waitcnt vmcnt(0)" ::: "memory");
        }
        asm volatile("s_barrier" ::: "memory");
        const char* ab = smem + cur * 8192;
        const char* bb = smem + 16384 + cur * 16384;
        #pragma unroll
        for (int ks2 = 0; ks2 < 2; ++ks2) {
            const int cb = (((ks2 * 4 + l4) ^ (l15 & 7)) << 4);
            bf16x8 a[4], bg[2];
            #pragma unroll
            for (int r = 0; r < 4; ++r)
                a[r] = *(const bf16x8*)(ab + (r * 16 + l15) * 128 + cb);
            bg[0] = *(const bf16x8*)(bb + (wave * 32 + l15) * 128 + cb);
            bg[1] = *(const bf16x8*)(bb + (wave * 32 + 16 + l15) * 128 + cb);
            #pragma unroll
            for (int r = 0; r < 4; ++r) {
                acc1[r][0] = __builtin_amdgcn_mfma_f32_16x16x32_bf16(a[r], bg[0], acc1[r][0], 0, 0, 0);
                acc1[r][1] = __builtin_amdgcn_mfma_f32_16x16x32_bf16(a[r], bg[1], acc1[r][1], 0, 0, 0);
            }
        }
        asm volatile("s_waitcnt lgkmcnt(0)\n\ts_barrier" ::: "memory");
    }

    // kick off first W2 slice while we do GELU/LN
    STAGE2(0, 0);

    // ================= bias + exact GELU (in regs) + LN partials =================
    const float* b1e = b1 + e * HDIM;
    const int c0 = wave * 32 + l15, c1 = c0 + 16;
    float bias0 = b1e[c0], bias1 = b1e[c1];
    #pragma unroll
    for (int r = 0; r < 4; ++r)
        #pragma unroll
        for (int i = 0; i < 4; ++i) {
            int row = r * 16 + l4 * 4 + i;
            float v0 = acc1[r][0][i] + bias0;
            float v1 = acc1[r][1][i] + bias1;
            v0 = 0.5f * v0 * (1.0f + erff(v0 * 0.70710678f));
            v1 = 0.5f * v1 * (1.0f + erff(v1 * 0.70710678f));
            acc1[r][0][i] = v0; acc1[r][1][i] = v1;
            float s = v0 + v1, ss = v0 * v0 + v1 * v1;
            s  += __shfl_xor(s, 1);  s  += __shfl_xor(s, 2);
            s  += __shfl_xor(s, 4);  s  += __shfl_xor(s, 8);
            ss += __shfl_xor(ss, 1); ss += __shfl_xor(ss, 2);
            ss += __shfl_xor(ss, 4); ss += __shfl_xor(ss, 8);
            if (l15 == 0) {
                *(float*)(smem + 49152 + row * 32 + wave * 8)     = s;
                *(float*)(smem + 49152 + row * 32 + wave * 8 + 4) = ss;
            }
        }
    asm volatile("s_waitcnt lgkmcnt(0)\n\ts_barrier" ::: "memory");

    // ================= LN apply (gate weight folded in) -> h_ln bf16 swizzled =================
    {
        const float* lge = ln_g + e * HDIM;
        const float* lbe = ln_b + e * HDIM;
        float g0 = lge[c0], g1 = lge[c1], be0 = lbe[c0], be1 = lbe[c1];
        #pragma unroll
        for (int r = 0; r < 4; ++r)
            #pragma unroll
            for (int i = 0; i < 4; ++i) {
                int row = r * 16 + l4 * 4 + i;
                float4 p0 = *(const float4*)(smem + 49152 + row * 32);
                float4 p1 = *(const float4*)(smem + 49152 + row * 32 + 16);
                float s  = p0.x + p0.z + p1.x + p1.z;
                float ss = p0.y + p0.w + p1.y + p1.w;
                float mean = s * 0.0078125f;
                float var  = fmaf(-mean, mean, ss * 0.0078125f);
                float rstd = rsqrtf(var + 1e-5f);
                float w = *(const float*)(smem + 51456 + row * 4);
                float h0 = ((acc1[r][0][i] - mean) * rstd * g0 + be0) * w;
                float h1 = ((acc1[r][1][i] - mean) * rstd * g1 + be1) * w;
                int wr = (row & 7) << 4;
                *(unsigned short*)(smem + row * 256 + ((c0 * 2) ^ wr)) = f2bf(h0);
                *(unsigned short*)(smem + row * 256 + ((c1 * 2) ^ wr)) = f2bf(h1);
            }
    }
    asm volatile("s_waitcnt lgkmcnt(0)\n\ts_barrier" ::: "memory");

    // ================= hoist GEMM2 A fragments to registers =================
    bf16x8 A2[4][4];
    #pragma unroll
    for (int r = 0; r < 4; ++r)
        #pragma unroll
        for (int kk = 0; kk < 4; ++kk)
            A2[r][kk] = *(const bf16x8*)(smem + (r * 16 + l15) * 256 + ((((kk * 4 + l4) ^ (l15 & 7))) << 4));
    asm volatile("s_waitcnt lgkmcnt(0)\n\ts_barrier" ::: "memory");   // h_ln region now reusable as patches

    // ================= GEMM2: contrib = h_ln @ W2[e], barrier-free =================
    STAGE2(1, 1);
    char* patch = smem + wave * 3072;   // 64 rows x 48B (16 cols bf16 + pad)
    const int rsoff = (*(const int*)(smem + 51200 + lane * 4)) << 10;
    char* cw = (char*)contrib + rsoff + wave * 32;

    #pragma unroll
    for (int ns = 0; ns < 8; ++ns) {
        if (ns < 7) {
            asm volatile("s_waitcnt lgkmcnt(0)" ::: "memory");
            if (ns > 0) STAGE2(ns + 1, (ns + 1) & 1);
        }
        if (ns == 0)      asm volatile("s_waitcnt vmcnt(4)" ::: "memory");
        else if (ns < 7)  asm volatile("s_waitcnt vmcnt(6)" ::: "memory");
        else              asm volatile("s_waitcnt vmcnt(2)" ::: "memory");

        const char* bb = smem + 16384 + (ns & 1) * 16384;
        bf16x8 Bf[4];
        #pragma unroll
        for (int kk = 0; kk < 4; ++kk)
            Bf[kk] = *(const bf16x8*)(bb + (wave * 16 + l15) * 256 + ((((kk * 4 + l4) ^ (l15 & 7))) << 4));

        f32x4 acc2[4];
        #pragma unroll
        for (int r = 0; r < 4; ++r) acc2[r] = (f32x4){0.f, 0.f, 0.f, 0.f};
        #pragma unroll
        for (int kk = 0; kk < 4; ++kk)
            #pragma unroll
            for (int r = 0; r < 4; ++r)
                acc2[r] = __builtin_amdgcn_mfma_f32_16x16x32_bf16(A2[r][kk], Bf[kk], acc2[r], 0, 0, 0);

        // epilogue through per-wave LDS patch -> 2 vector stores
        #pragma unroll
        for (int r = 0; r < 4; ++r)
            #pragma unroll
            for (int i = 0; i < 4; ++i)
                *(unsigned short*)(patch + (r * 16 + l4 * 4 + i) * 48 + l15 * 2) = f2bf(acc2[r][i]);
        bf16x8 p0 = *(const bf16x8*)(patch + lane * 48);
        bf16x8 p1 = *(const bf16x8*)(patch + lane * 48 + 16);
        *(bf16x8*)(cw + ns * 128)      = p0;
        *(bf16x8*)(cw + ns * 128 + 16) = p1;
    }
#undef STAGE1
#undef STAGE2
}

// ---------------- combine top-2 ----------------
__global__ __launch_bounds__(256)
void combine_kernel(const unsigned short* __restrict__ contrib, const int* __restrict__ topk_e,
                    const float* __restrict__ topk_w, const float* __restrict__ b2,
                    float* __restrict__ out) {
    int idx = blockIdx.x * 256 + threadIdx.x;
    int row = idx >> 6;
    int cb = (idx & 63) << 3;
    int e0 = topk_e[row * 2], e1 = topk_e[row * 2 + 1];
    float w0 = topk_w[row * 2], w1 = topk_w[row * 2 + 1];
    bf16x8 c0 = *reinterpret_cast<const bf16x8*>(contrib + (size_t)row * 1024 + cb);
    bf16x8 c1 = *reinterpret_cast<const bf16x8*>(contrib + (size_t)row * 1024 + 512 + cb);
    const float* b20 = b2 + e0 * ODIM + cb;
    const float* b21 = b2 + e1 * ODIM + cb;
    float res[8];
    #pragma unroll
    for (int j = 0; j < 8; ++j)
        res[j] = bf2f((unsigned short)c0[j]) + bf2f((unsigned short)c1[j]) + w0 * b20[j] + w1 * b21[j];
    float4 o0 = {res[0], res[1], res[2], res[3]};
    float4 o1 = {res[4], res[5], res[6], res[7]};
    *reinterpret_cast<float4*>(out + (size_t)row * ODIM + cb) = o0;
    *reinterpret_cast<float4*>(out + (size_t)row * ODIM + cb + 4) = o1;
}

extern "C" void kernel_launch(void* const* d_in, const int* in_sizes, int n_in,
                              void* d_out, int out_size, void* d_ws, size_t ws_size,
                              hipStream_t stream) {
    const float* x    = (const float*)d_in[0];
    const float* gW   = (const float*)d_in[1];
    const float* gb   = (const float*)d_in[2];
    const float* W1   = (const float*)d_in[3];
    const float* b1   = (const float*)d_in[4];
    const float* ln_g = (const float*)d_in[5];
    const float* ln_b = (const float*)d_in[6];
    const float* W2   = (const float*)d_in[7];
    const float* b2   = (const float*)d_in[8];
    float* out = (float*)d_out;

    char* ws = (char*)d_ws;
    int*   cnt      = (int*)(ws);                    // 64 B
    float* ent_acc  = (float*)(ws + 64);             // 4 B
    int*   tiledesc = (int*)(ws + 128);              // 528*4 = 2112 B (ends 2240)
    int*   topk_e   = (int*)(ws + 4096);             // 128 KB (ends 135168)
    float* topk_w   = (float*)(ws + 135168);         // 128 KB (ends 266240)
    int*   bucket   = (int*)(ws + 266240);           // 1 MB  (ends 1314816)
    unsigned short* xb      = (unsigned short*)(ws + 1314816);   // 16 MB (ends 18092032)
    unsigned short* w1b     = (unsigned short*)(ws + 18092032);  // 2 MB
    unsigned short* w2t     = (unsigned short*)(ws + 20189184);  // 2 MB
    unsigned short* contrib = (unsigned short*)(ws + 22286336);  // 32 MB
    // gwT (32 KB f32) aliases the head of contrib: gate reads it before ffn writes contrib
    float* gwT = (float*)(ws + 22286336);

    hipMemsetAsync(ws, 0, 256, stream);

    gwt_prep<<<32, 256, 0, stream>>>(gW, gwT);
    w1_prep<<<dim3(4, 8, NEXP), 256, 0, stream>>>(W1, w1b);
    transpose_to_bf16<<<dim3(ODIM / 32, HDIM / 32, NEXP), dim3(32, 8), 0, stream>>>(W2, w2t, HDIM, ODIM);
    gate_kernel<<<BROWS / 16, 256, 0, stream>>>(x, gwT, gb, cnt, ent_acc, bucket, topk_e, topk_w, xb);
    aux_kernel<<<1, 64, 0, stream>>>(cnt, ent_acc, out + (out_size - 1), tiledesc);
    ffn_kernel<<<MAXTILES, 256, 0, stream>>>(xb, w1b, w2t, b1, ln_g, ln_b, topk_w, cnt, bucket, tiledesc, contrib);
    combine_kernel<<<(BROWS * ODIM / 8) / 256, 256, 0, stream>>>(contrib, topk_e, topk_w, b2, out);
}

// Round 8
// 99.320 us; speedup vs baseline: 1.5446x; 1.0943x over previous
//
#include <hip/hip_runtime.h>

#define BROWS 16384
#define DDIM  512
#define NEXP  16
#define HDIM  128
#define ODIM  512
#define MAXTILES 528

typedef __attribute__((ext_vector_type(8))) short bf16x8;
typedef __attribute__((ext_vector_type(4))) float f32x4;

typedef const __attribute__((address_space(1))) unsigned GA;
typedef __attribute__((address_space(3))) unsigned LA;
#define GLD16(g, l) __builtin_amdgcn_global_load_lds((GA*)(g), (LA*)(l), 16, 0, 0)

static __device__ __forceinline__ unsigned short f2bf(float f) {
    union { float f; unsigned u; } v; v.f = f;
    unsigned r = v.u + 0x7fffu + ((v.u >> 16) & 1u);
    return (unsigned short)(r >> 16);
}
static __device__ __forceinline__ float bf2f(unsigned short h) {
    union { unsigned u; float f; } v; v.u = ((unsigned)h) << 16;
    return v.f;
}

// ---------------- gW -> transposed f32 [16][512] ----------------
__global__ __launch_bounds__(256)
void gwt_prep(const float* __restrict__ in, float* __restrict__ out) {
    int i = blockIdx.x * 256 + threadIdx.x;   // 8192 elems
    int d = i >> 4, e = i & 15;
    out[e * 512 + d] = in[i];
}

// ---------------- W1 -> blocked bf16 [e][ks=8][c=128][k=64] ----------------
__global__ __launch_bounds__(256)
void w1_prep(const float* __restrict__ in, unsigned short* __restrict__ out) {
    __shared__ float tile[64][33];
    int e = blockIdx.z;
    int ks = blockIdx.y;
    int cb = blockIdx.x * 32;
    const float* src = in + ((size_t)e * 512 + ks * 64) * 128 + cb;
    int c = threadIdx.x & 31, r8 = threadIdx.x >> 5;
    #pragma unroll
    for (int p = 0; p < 8; ++p)
        tile[p * 8 + r8][c] = src[(size_t)(p * 8 + r8) * 128 + c];
    __syncthreads();
    int k = threadIdx.x & 63, c4 = threadIdx.x >> 6;
    unsigned short* dst = out + (((size_t)e * 8 + ks) * 128 + cb) * 64;
    #pragma unroll
    for (int p = 0; p < 8; ++p)
        dst[(size_t)(c4 + p * 4) * 64 + k] = f2bf(tile[k][c4 + p * 4]);
}

// ---------------- transpose W2 to bf16 [e][O][H] ----------------
__global__ __launch_bounds__(256)
void transpose_to_bf16(const float* __restrict__ in, unsigned short* __restrict__ out, int R, int C) {
    __shared__ float tile[32][33];
    int e = blockIdx.z;
    in  += (size_t)e * R * C;
    out += (size_t)e * R * C;
    int c0 = blockIdx.x * 32, r0 = blockIdx.y * 32;
    for (int i = threadIdx.y; i < 32; i += 8)
        tile[i][threadIdx.x] = in[(size_t)(r0 + i) * C + c0 + threadIdx.x];
    __syncthreads();
    for (int i = threadIdx.y; i < 32; i += 8)
        out[(size_t)(c0 + i) * R + r0 + threadIdx.x] = f2bf(tile[threadIdx.x][i]);
}

// ---------------- gating (fused x->bf16), lane = (expert, d-quarter) ----------------
// 1024 blocks x 256 threads; 16 rows/block, 4 rows/wave (one per dq group).
__global__ __launch_bounds__(256)
void gate_kernel(const float* __restrict__ x, const float* __restrict__ gwTg,
                 const float* __restrict__ gb,
                 int* cnt, float* ent_acc, int* bucket, int* topk_e, float* topk_w,
                 unsigned short* __restrict__ xb) {
    __shared__ __align__(16) float xs[16][4][132];   // [row][dq][128+pad]
    __shared__ int lcnt[16];
    __shared__ int gbase[16];
    __shared__ int entpack[32];
    __shared__ float entf;

    const int tid = threadIdx.x;
    const int rb = blockIdx.x * 16;

    // stage x tile (coalesced) + fused bf16 conversion
    #pragma unroll
    for (int k = 0; k < 8; ++k) {
        int idx = tid + k * 256;            // float4 index within [16][128]
        int row = idx >> 7, c4 = idx & 127;
        float4 v = *reinterpret_cast<const float4*>(x + (size_t)(rb + row) * DDIM + c4 * 4);
        int dq = c4 >> 5, j = c4 & 31;
        *reinterpret_cast<float4*>(&xs[row][dq][j * 4]) = v;
        uint2 p;
        p.x = (unsigned)f2bf(v.x) | ((unsigned)f2bf(v.y) << 16);
        p.y = (unsigned)f2bf(v.z) | ((unsigned)f2bf(v.w) << 16);
        *reinterpret_cast<uint2*>(xb + (size_t)(rb + row) * DDIM + c4 * 4) = p;
    }
    if (tid < 16) lcnt[tid] = 0;
    if (tid == 0) entf = 0.f;

    const int wave = tid >> 6, lane = tid & 63;
    const int e = lane & 15, dq = lane >> 4;
    const int r0 = wave * 4;

    const float4* gw4 = reinterpret_cast<const float4*>(gwTg) + e * 128 + dq * 32;
    float gbe = gb[e];
    __syncthreads();

    float a0 = 0.f, a1 = 0.f, a2 = 0.f, a3 = 0.f;
    #pragma unroll
    for (int j = 0; j < 32; ++j) {
        float4 g  = gw4[j];
        float4 v0 = *reinterpret_cast<const float4*>(&xs[r0 + 0][dq][j * 4]);
        float4 v1 = *reinterpret_cast<const float4*>(&xs[r0 + 1][dq][j * 4]);
        float4 v2 = *reinterpret_cast<const float4*>(&xs[r0 + 2][dq][j * 4]);
        float4 v3 = *reinterpret_cast<const float4*>(&xs[r0 + 3][dq][j * 4]);
        a0 = fmaf(v0.x, g.x, a0); a0 = fmaf(v0.y, g.y, a0); a0 = fmaf(v0.z, g.z, a0); a0 = fmaf(v0.w, g.w, a0);
        a1 = fmaf(v1.x, g.x, a1); a1 = fmaf(v1.y, g.y, a1); a1 = fmaf(v1.z, g.z, a1); a1 = fmaf(v1.w, g.w, a1);
        a2 = fmaf(v2.x, g.x, a2); a2 = fmaf(v2.y, g.y, a2); a2 = fmaf(v2.z, g.z, a2); a2 = fmaf(v2.w, g.w, a2);
        a3 = fmaf(v3.x, g.x, a3); a3 = fmaf(v3.y, g.y, a3); a3 = fmaf(v3.z, g.z, a3); a3 = fmaf(v3.w, g.w, a3);
    }
    // reduce across the 4 dq groups (every lane ends with full sums)
    a0 += __shfl_xor(a0, 16); a0 += __shfl_xor(a0, 32);
    a1 += __shfl_xor(a1, 16); a1 += __shfl_xor(a1, 32);
    a2 += __shfl_xor(a2, 16); a2 += __shfl_xor(a2, 32);
    a3 += __shfl_xor(a3, 16); a3 += __shfl_xor(a3, 32);

    // each dq group finalizes row r0+dq; all 64 lanes busy
    float sc = (dq == 0) ? a0 : (dq == 1) ? a1 : (dq == 2) ? a2 : a3;
    sc += gbe;

    // 16-lane top-2 (value,index) butterfly; tie -> lower index (matches seq scan)
    float v0 = sc, v1 = -1e30f;
    int   i0 = e,  i1 = 255;
    #pragma unroll
    for (int k = 1; k <= 8; k <<= 1) {
        float o0 = __shfl_xor(v0, k), o1 = __shfl_xor(v1, k);
        int   oi0 = __shfl_xor(i0, k), oi1 = __shfl_xor(i1, k);
        bool gt = (o0 > v0) || (o0 == v0 && oi0 < i0);
        float n0 = gt ? o0 : v0;  int ni0 = gt ? oi0 : i0;
        float c  = gt ? v0 : o0;  int ci  = gt ? i0 : oi0;
        float d  = gt ? o1 : v1;  int di_ = gt ? oi1 : i1;
        bool g2 = (c > d) || (c == d && ci < di_);
        v0 = n0; i0 = ni0;
        v1 = g2 ? c : d;  i1 = g2 ? ci : di_;
    }

    float t = sc - v0;
    float ex = expf(t);
    float Z = ex, S1 = ex * t;
    #pragma unroll
    for (int k = 1; k <= 8; k <<= 1) {
        Z  += __shfl_xor(Z, k);
        S1 += __shfl_xor(S1, k);
    }
    float entloc = logf(Z) - S1 / Z;
    float w0 = 1.0f / (1.0f + expf(v1 - v0));

    if (e == 0) {
        int row = rb + r0 + dq;
        topk_e[row * 2]     = i0;
        topk_e[row * 2 + 1] = i1;
        topk_w[row * 2]     = w0;
        topk_w[row * 2 + 1] = 1.0f - w0;
        int ib = r0 + dq;   // [0,16)
        int lp0 = atomicAdd(&lcnt[i0], 1);
        entpack[ib * 2]     = (row << 1) | (i0 << 15) | (lp0 << 19);
        int lp1 = atomicAdd(&lcnt[i1], 1);
        entpack[ib * 2 + 1] = ((row << 1) | 1) | (i1 << 15) | (lp1 << 19);
        atomicAdd(&entf, entloc);
    }
    __syncthreads();
    if (tid < 16) gbase[tid] = atomicAdd(&cnt[tid], lcnt[tid]);
    if (tid == 0) atomicAdd(ent_acc, entf);
    __syncthreads();
    if (tid < 32) {
        int p = entpack[tid];
        int rowslot = p & 0x7FFF;
        int ee = (p >> 15) & 15;
        int lpos = p >> 19;
        bucket[ee * BROWS + gbase[ee] + lpos] = rowslot;
    }
}

// ---------------- aux loss + dense tile table ----------------
__global__ void aux_kernel(const int* __restrict__ cnt, const float* __restrict__ ent_acc,
                           float* __restrict__ outp, int* __restrict__ tiledesc) {
    __shared__ int off[17];
    int tid = threadIdx.x;
    if (tid == 0) {
        float lb = 0.f;
        for (int k = 0; k < 16; ++k) {
            float u = (float)cnt[k] * (1.f / 16384.f) - 0.0625f;
            lb += u * u;
        }
        lb *= (1.f / 16.f);
        float ment = ent_acc[0] * (1.f / 16384.f);
        outp[0] = lb - 0.1f * ment;
        int o = 0;
        for (int e = 0; e < 16; ++e) { off[e] = o; o += (cnt[e] + 63) >> 6; }
        off[16] = o;
    }
    __syncthreads();
    #pragma unroll 1
    for (int e = 0; e < 16; ++e) {
        int nt = off[e + 1] - off[e];
        for (int i = tid; i < nt; i += 64)
            tiledesc[off[e] + i] = e | (i << 8);
    }
    for (int i = off[16] + tid; i < MAXTILES; i += 64)
        tiledesc[i] = -1;
}

// ---------------- grouped sparse FFN, pipelined, dense tile grid ----------------
__global__ __launch_bounds__(256, 2)
void ffn_kernel(const unsigned short* __restrict__ xb,
                const unsigned short* __restrict__ w1b,   // [E][8][128][64] bf16
                const unsigned short* __restrict__ w2t,   // [E][O][H] bf16
                const float* __restrict__ b1, const float* __restrict__ ln_g,
                const float* __restrict__ ln_b, const float* __restrict__ topk_w,
                const int* __restrict__ cnt, const int* __restrict__ bucket,
                const int* __restrict__ tiledesc,
                unsigned short* __restrict__ contrib) {
    int d = tiledesc[blockIdx.x];
    if (d < 0) return;
    int e = d & 255;
    int t = d >> 8;
    int n = cnt[e];
    int base = t * 64;
    int rows = n - base; if (rows > 64) rows = 64;

    __shared__ __align__(16) char smem[51712];

    const int tid = threadIdx.x;
    const int wave = tid >> 6, lane = tid & 63;
    const int l15 = lane & 15, l4 = lane >> 4;
    const int bbase = e * BROWS + base;

    if (tid < 64) {
        int idx = tid < rows ? tid : (rows - 1);
        int rs = bucket[bbase + idx];
        *(int*)(smem + 51200 + tid * 4) = rs;
        *(float*)(smem + 51456 + tid * 4) = topk_w[rs];
    }

    const int lsw = (((lane & 7) ^ ((lane >> 3) & 7)) << 4);
    int ar0 = wave * 16 + (lane >> 3);
    int ar1 = ar0 + 8;
    size_t grow0 = (size_t)(bucket[bbase + (ar0 < rows ? ar0 : rows - 1)] >> 1) * 1024;
    size_t grow1 = (size_t)(bucket[bbase + (ar1 < rows ? ar1 : rows - 1)] >> 1) * 1024;
    const char* xbp = (const char*)xb;
    const char* w1e = (const char*)w1b + (size_t)e * 131072;
    const char* w2e = (const char*)w2t + (size_t)e * 131072;
    const int sw2e = (((lane & 15) ^ (lane >> 4)) << 4);
    const int sw2o = sw2e ^ 64;

#define STAGE1(ks_, buf_) do { \
    char* ab_ = smem + (buf_) * 8192; \
    char* bb_ = smem + 16384 + (buf_) * 16384; \
    GLD16(xbp + grow0 + (ks_) * 128 + lsw, ab_ + (wave * 2 + 0) * 1024); \
    GLD16(xbp + grow1 + (ks_) * 128 + lsw, ab_ + (wave * 2 + 1) * 1024); \
    const char* s1_ = w1e + (ks_) * 16384 + ((lane >> 3) << 7) + lsw; \
    GLD16(s1_ + (wave * 4 + 0) * 1024, bb_ + (wave * 4 + 0) * 1024); \
    GLD16(s1_ + (wave * 4 + 1) * 1024, bb_ + (wave * 4 + 1) * 1024); \
    GLD16(s1_ + (wave * 4 + 2) * 1024, bb_ + (wave * 4 + 2) * 1024); \
    GLD16(s1_ + (wave * 4 + 3) * 1024, bb_ + (wave * 4 + 3) * 1024); \
} while (0)

#define STAGE2(ns_, buf_) do { \
    char* bb_ = smem + 16384 + (buf_) * 16384; \
    const char* s2_ = w2e + (size_t)(ns_) * 16384 + ((lane >> 4) << 8); \
    GLD16(s2_ + (wave * 4 + 0) * 1024 + sw2e, bb_ + (wave * 4 + 0) * 1024); \
    GLD16(s2_ + (wave * 4 + 1) * 1024 + sw2o, bb_ + (wave * 4 + 1) * 1024); \
    GLD16(s2_ + (wave * 4 + 2) * 1024 + sw2e, bb_ + (wave * 4 + 2) * 1024); \
    GLD16(s2_ + (wave * 4 + 3) * 1024 + sw2o, bb_ + (wave * 4 + 3) * 1024); \
} while (0)

    // ================= GEMM1: h = x_tile @ W1[e] =================
    STAGE1(0, 0);
    f32x4 acc1[4][2];
    #pragma unroll
    for (int r = 0; r < 4; ++r)
        #pragma unroll
        for (int c = 0; c < 2; ++c)
            acc1[r][c] = (f32x4){0.f, 0.f, 0.f, 0.f};

    #pragma unroll
    for (int ks = 0; ks < 8; ++ks) {
        const int cur = ks & 1;
        if (ks < 7) {
            STAGE1(ks + 1, cur ^ 1);
            asm volatile("s_waitcnt vmcnt(6)" ::: "memory");
        } else {
            asm volatile("s_waitcnt vmcnt(0)" ::: "memory");
        }
        asm volatile("s_barrier" ::: "memory");
        const char* ab = smem + cur * 8192;
        const char* bb = smem + 16384 + cur * 16384;
        #pragma unroll
        for (int ks2 = 0; ks2 < 2; ++ks2) {
            const int cb = (((ks2 * 4 + l4) ^ (l15 & 7)) << 4);
            bf16x8 a[4], bg[2];
            #pragma unroll
            for (int r = 0; r < 4; ++r)
                a[r] = *(const bf16x8*)(ab + (r * 16 + l15) * 128 + cb);
            bg[0] = *(const bf16x8*)(bb + (wave * 32 + l15) * 128 + cb);
            bg[1] = *(const bf16x8*)(bb + (wave * 32 + 16 + l15) * 128 + cb);
            #pragma unroll
            for (int r = 0; r < 4; ++r) {
                acc1[r][0] = __builtin_amdgcn_mfma_f32_16x16x32_bf16(a[r], bg[0], acc1[r][0], 0, 0, 0);
                acc1[r][1] = __builtin_amdgcn_mfma_f32_16x16x32_bf16(a[r], bg[1], acc1[r][1], 0, 0, 0);
            }
        }
        asm volatile("s_waitcnt lgkmcnt(0)\n\ts_barrier" ::: "memory");
    }

    // kick off first W2 slice while we do GELU/LN
    STAGE2(0, 0);

    // ================= bias + exact GELU (in regs) + LN partials =================
    const float* b1e = b1 + e * HDIM;
    const int c0 = wave * 32 + l15, c1 = c0 + 16;
    float bias0 = b1e[c0], bias1 = b1e[c1];
    #pragma unroll
    for (int r = 0; r < 4; ++r)
        #pragma unroll
        for (int i = 0; i < 4; ++i) {
            int row = r * 16 + l4 * 4 + i;
            float v0 = acc1[r][0][i] + bias0;
            float v1 = acc1[r][1][i] + bias1;
            v0 = 0.5f * v0 * (1.0f + erff(v0 * 0.70710678f));
            v1 = 0.5f * v1 * (1.0f + erff(v1 * 0.70710678f));
            acc1[r][0][i] = v0; acc1[r][1][i] = v1;
            float s = v0 + v1, ss = v0 * v0 + v1 * v1;
            s  += __shfl_xor(s, 1);  s  += __shfl_xor(s, 2);
            s  += __shfl_xor(s, 4);  s  += __shfl_xor(s, 8);
            ss += __shfl_xor(ss, 1); ss += __shfl_xor(ss, 2);
            ss += __shfl_xor(ss, 4); ss += __shfl_xor(ss, 8);
            if (l15 == 0) {
                *(float*)(smem + 49152 + row * 32 + wave * 8)     = s;
                *(float*)(smem + 49152 + row * 32 + wave * 8 + 4) = ss;
            }
        }
    asm volatile("s_waitcnt lgkmcnt(0)\n\ts_barrier" ::: "memory");

    // ================= LN apply (gate weight folded in) -> h_ln bf16 swizzled =================
    {
        const float* lge = ln_g + e * HDIM;
        const float* lbe = ln_b + e * HDIM;
        float g0 = lge[c0], g1 = lge[c1], be0 = lbe[c0], be1 = lbe[c1];
        #pragma unroll
        for (int r = 0; r < 4; ++r)
            #pragma unroll
            for (int i = 0; i < 4; ++i) {
                int row = r * 16 + l4 * 4 + i;
                float4 p0 = *(const float4*)(smem + 49152 + row * 32);
                float4 p1 = *(const float4*)(smem + 49152 + row * 32 + 16);
                float s  = p0.x + p0.z + p1.x + p1.z;
                float ss = p0.y + p0.w + p1.y + p1.w;
                float mean = s * 0.0078125f;
                float var  = fmaf(-mean, mean, ss * 0.0078125f);
                float rstd = rsqrtf(var + 1e-5f);
                float w = *(const float*)(smem + 51456 + row * 4);
                float h0 = ((acc1[r][0][i] - mean) * rstd * g0 + be0) * w;
                float h1 = ((acc1[r][1][i] - mean) * rstd * g1 + be1) * w;
                int wr = (row & 7) << 4;
                *(unsigned short*)(smem + row * 256 + ((c0 * 2) ^ wr)) = f2bf(h0);
                *(unsigned short*)(smem + row * 256 + ((c1 * 2) ^ wr)) = f2bf(h1);
            }
    }
    asm volatile("s_waitcnt lgkmcnt(0)\n\ts_barrier" ::: "memory");

    // ================= hoist GEMM2 A fragments to registers =================
    bf16x8 A2[4][4];
    #pragma unroll
    for (int r = 0; r < 4; ++r)
        #pragma unroll
        for (int kk = 0; kk < 4; ++kk)
            A2[r][kk] = *(const bf16x8*)(smem + (r * 16 + l15) * 256 + ((((kk * 4 + l4) ^ (l15 & 7))) << 4));
    asm volatile("s_waitcnt lgkmcnt(0)\n\ts_barrier" ::: "memory");   // h_ln region now reusable as patches

    // ================= GEMM2: contrib = h_ln @ W2[e], barrier-free =================
    STAGE2(1, 1);
    char* patch = smem + wave * 3072;   // 64 rows x 48B (16 cols bf16 + pad)
    const int rsoff = (*(const int*)(smem + 51200 + lane * 4)) << 10;
    char* cw = (char*)contrib + rsoff + wave * 32;

    #pragma unroll
    for (int ns = 0; ns < 8; ++ns) {
        if (ns < 7) {
            asm volatile("s_waitcnt lgkmcnt(0)" ::: "memory");
            if (ns > 0) STAGE2(ns + 1, (ns + 1) & 1);
        }
        if (ns == 0)      asm volatile("s_waitcnt vmcnt(4)" ::: "memory");
        else if (ns < 7)  asm volatile("s_waitcnt vmcnt(6)" ::: "memory");
        else              asm volatile("s_waitcnt vmcnt(2)" ::: "memory");

        const char* bb = smem + 16384 + (ns & 1) * 16384;
        bf16x8 Bf[4];
        #pragma unroll
        for (int kk = 0; kk < 4; ++kk)
            Bf[kk] = *(const bf16x8*)(bb + (wave * 16 + l15) * 256 + ((((kk * 4 + l4) ^ (l15 & 7))) << 4));

        f32x4 acc2[4];
        #pragma unroll
        for (int r = 0; r < 4; ++r) acc2[r] = (f32x4){0.f, 0.f, 0.f, 0.f};
        #pragma unroll
        for (int kk = 0; kk < 4; ++kk)
            #pragma unroll
            for (int r = 0; r < 4; ++r)
                acc2[r] = __builtin_amdgcn_mfma_f32_16x16x32_bf16(A2[r][kk], Bf[kk], acc2[r], 0, 0, 0);

        // epilogue through per-wave LDS patch -> 2 vector stores
        #pragma unroll
        for (int r = 0; r < 4; ++r)
            #pragma unroll
            for (int i = 0; i < 4; ++i)
                *(unsigned short*)(patch + (r * 16 + l4 * 4 + i) * 48 + l15 * 2) = f2bf(acc2[r][i]);
        bf16x8 p0 = *(const bf16x8*)(patch + lane * 48);
        bf16x8 p1 = *(const bf16x8*)(patch + lane * 48 + 16);
        *(bf16x8*)(cw + ns * 128)      = p0;
        *(bf16x8*)(cw + ns * 128 + 16) = p1;
    }
#undef STAGE1
#undef STAGE2
}

// ---------------- combine top-2 ----------------
__global__ __launch_bounds__(256)
void combine_kernel(const unsigned short* __restrict__ contrib, const int* __restrict__ topk_e,
                    const float* __restrict__ topk_w, const float* __restrict__ b2,
                    float* __restrict__ out) {
    int idx = blockIdx.x * 256 + threadIdx.x;
    int row = idx >> 6;
    int cb = (idx & 63) << 3;
    int e0 = topk_e[row * 2], e1 = topk_e[row * 2 + 1];
    float w0 = topk_w[row * 2], w1 = topk_w[row * 2 + 1];
    bf16x8 c0 = *reinterpret_cast<const bf16x8*>(contrib + (size_t)row * 1024 + cb);
    bf16x8 c1 = *reinterpret_cast<const bf16x8*>(contrib + (size_t)row * 1024 + 512 + cb);
    const float* b20 = b2 + e0 * ODIM + cb;
    const float* b21 = b2 + e1 * ODIM + cb;
    float res[8];
    #pragma unroll
    for (int j = 0; j < 8; ++j)
        res[j] = bf2f((unsigned short)c0[j]) + bf2f((unsigned short)c1[j]) + w0 * b20[j] + w1 * b21[j];
    float4 o0 = {res[0], res[1], res[2], res[3]};
    float4 o1 = {res[4], res[5], res[6], res[7]};
    *reinterpret_cast<float4*>(out + (size_t)row * ODIM + cb) = o0;
    *reinterpret_cast<float4*>(out + (size_t)row * ODIM + cb + 4) = o1;
}

extern "C" void kernel_launch(void* const* d_in, const int* in_sizes, int n_in,
                              void* d_out, int out_size, void* d_ws, size_t ws_size,
                              hipStream_t stream) {
    const float* x    = (const float*)d_in[0];
    const float* gW   = (const float*)d_in[1];
    const float* gb   = (const float*)d_in[2];
    const float* W1   = (const float*)d_in[3];
    const float* b1   = (const float*)d_in[4];
    const float* ln_g = (const float*)d_in[5];
    const float* ln_b = (const float*)d_in[6];
    const float* W2   = (const float*)d_in[7];
    const float* b2   = (const float*)d_in[8];
    float* out = (float*)d_out;

    char* ws = (char*)d_ws;
    int*   cnt      = (int*)(ws);                    // 64 B
    float* ent_acc  = (float*)(ws + 64);             // 4 B
    int*   tiledesc = (int*)(ws + 128);              // 528*4 = 2112 B
    int*   topk_e   = (int*)(ws + 4096);             // 128 KB
    float* topk_w   = (float*)(ws + 135168);         // 128 KB
    int*   bucket   = (int*)(ws + 266240);           // 1 MB
    unsigned short* xb      = (unsigned short*)(ws + 1314816);   // 16 MB
    unsigned short* w1b     = (unsigned short*)(ws + 18092032);  // 2 MB
    unsigned short* w2t     = (unsigned short*)(ws + 20189184);  // 2 MB
    unsigned short* contrib = (unsigned short*)(ws + 22286336);  // 32 MB
    // gwT (32 KB f32) aliases the head of contrib: gate reads it before ffn writes contrib
    float* gwT = (float*)(ws + 22286336);

    hipMemsetAsync(ws, 0, 256, stream);

    gwt_prep<<<32, 256, 0, stream>>>(gW, gwT);
    w1_prep<<<dim3(4, 8, NEXP), 256, 0, stream>>>(W1, w1b);
    transpose_to_bf16<<<dim3(ODIM / 32, HDIM / 32, NEXP), dim3(32, 8), 0, stream>>>(W2, w2t, HDIM, ODIM);
    gate_kernel<<<BROWS / 16, 256, 0, stream>>>(x, gwT, gb, cnt, ent_acc, bucket, topk_e, topk_w, xb);
    aux_kernel<<<1, 64, 0, stream>>>(cnt, ent_acc, out + (out_size - 1), tiledesc);
    ffn_kernel<<<MAXTILES, 256, 0, stream>>>(xb, w1b, w2t, b1, ln_g, ln_b, topk_w, cnt, bucket, tiledesc, contrib);
    combine_kernel<<<(BROWS * ODIM / 8) / 256, 256, 0, stream>>>(contrib, topk_e, topk_w, b2, out);
}

// Round 9
// 97.306 us; speedup vs baseline: 1.5766x; 1.0207x over previous
//
#include <hip/hip_runtime.h>

#define BROWS 16384
#define DDIM  512
#define NEXP  16
#define HDIM  128
#define ODIM  512
#define MAXTILES 528

typedef __attribute__((ext_vector_type(8))) short bf16x8;
typedef __attribute__((ext_vector_type(4))) float f32x4;

typedef const __attribute__((address_space(1))) unsigned GA;
typedef __attribute__((address_space(3))) unsigned LA;
#define GLD16(g, l) __builtin_amdgcn_global_load_lds((GA*)(g), (LA*)(l), 16, 0, 0)

static __device__ __forceinline__ unsigned short f2bf(float f) {
    union { float f; unsigned u; } v; v.f = f;
    unsigned r = v.u + 0x7fffu + ((v.u >> 16) & 1u);
    return (unsigned short)(r >> 16);
}
static __device__ __forceinline__ float bf2f(unsigned short h) {
    union { unsigned u; float f; } v; v.u = ((unsigned)h) << 16;
    return v.f;
}

// ---------------- gW -> transposed f32 [16][512]; also zeroes cnt/ent_acc ----------------
__global__ __launch_bounds__(256)
void gwt_prep(const float* __restrict__ in, float* __restrict__ out,
              int* __restrict__ cnt, float* __restrict__ ent_acc) {
    int i = blockIdx.x * 256 + threadIdx.x;   // 8192 elems
    if (blockIdx.x == 0) {
        if (threadIdx.x < 16) cnt[threadIdx.x] = 0;
        if (threadIdx.x == 16) ent_acc[0] = 0.f;
    }
    int d = i >> 4, e = i & 15;
    out[e * 512 + d] = in[i];
}

// ---------------- W1 -> blocked bf16 [e][ks=8][c=128][k=64] ----------------
__global__ __launch_bounds__(256)
void w1_prep(const float* __restrict__ in, unsigned short* __restrict__ out) {
    __shared__ float tile[64][33];
    int e = blockIdx.z;
    int ks = blockIdx.y;
    int cb = blockIdx.x * 32;
    const float* src = in + ((size_t)e * 512 + ks * 64) * 128 + cb;
    int c = threadIdx.x & 31, r8 = threadIdx.x >> 5;
    #pragma unroll
    for (int p = 0; p < 8; ++p)
        tile[p * 8 + r8][c] = src[(size_t)(p * 8 + r8) * 128 + c];
    __syncthreads();
    int k = threadIdx.x & 63, c4 = threadIdx.x >> 6;
    unsigned short* dst = out + (((size_t)e * 8 + ks) * 128 + cb) * 64;
    #pragma unroll
    for (int p = 0; p < 8; ++p)
        dst[(size_t)(c4 + p * 4) * 64 + k] = f2bf(tile[k][c4 + p * 4]);
}

// ---------------- transpose W2 to bf16 [e][O][H] ----------------
__global__ __launch_bounds__(256)
void transpose_to_bf16(const float* __restrict__ in, unsigned short* __restrict__ out, int R, int C) {
    __shared__ float tile[32][33];
    int e = blockIdx.z;
    in  += (size_t)e * R * C;
    out += (size_t)e * R * C;
    int c0 = blockIdx.x * 32, r0 = blockIdx.y * 32;
    for (int i = threadIdx.y; i < 32; i += 8)
        tile[i][threadIdx.x] = in[(size_t)(r0 + i) * C + c0 + threadIdx.x];
    __syncthreads();
    for (int i = threadIdx.y; i < 32; i += 8)
        out[(size_t)(c0 + i) * R + r0 + threadIdx.x] = f2bf(tile[threadIdx.x][i]);
}

// ---------------- gating (fused x->bf16), lane = (expert, d-quarter) ----------------
__global__ __launch_bounds__(256)
void gate_kernel(const float* __restrict__ x, const float* __restrict__ gwTg,
                 const float* __restrict__ gb,
                 int* cnt, float* ent_acc, int* bucket, int* topk_e, float* topk_w,
                 unsigned short* __restrict__ xb) {
    __shared__ __align__(16) float xs[16][4][132];   // [row][dq][128+pad]
    __shared__ int lcnt[16];
    __shared__ int gbase[16];
    __shared__ int entpack[32];
    __shared__ float entf;

    const int tid = threadIdx.x;
    const int rb = blockIdx.x * 16;

    // stage x tile (coalesced) + fused bf16 conversion
    #pragma unroll
    for (int k = 0; k < 8; ++k) {
        int idx = tid + k * 256;            // float4 index within [16][128]
        int row = idx >> 7, c4 = idx & 127;
        float4 v = *reinterpret_cast<const float4*>(x + (size_t)(rb + row) * DDIM + c4 * 4);
        int dq = c4 >> 5, j = c4 & 31;
        *reinterpret_cast<float4*>(&xs[row][dq][j * 4]) = v;
        uint2 p;
        p.x = (unsigned)f2bf(v.x) | ((unsigned)f2bf(v.y) << 16);
        p.y = (unsigned)f2bf(v.z) | ((unsigned)f2bf(v.w) << 16);
        *reinterpret_cast<uint2*>(xb + (size_t)(rb + row) * DDIM + c4 * 4) = p;
    }
    if (tid < 16) lcnt[tid] = 0;
    if (tid == 0) entf = 0.f;

    const int wave = tid >> 6, lane = tid & 63;
    const int e = lane & 15, dq = lane >> 4;
    const int r0 = wave * 4;

    const float4* gw4 = reinterpret_cast<const float4*>(gwTg) + e * 128 + dq * 32;
    float gbe = gb[e];
    __syncthreads();

    float a0 = 0.f, a1 = 0.f, a2 = 0.f, a3 = 0.f;
    #pragma unroll
    for (int j = 0; j < 32; ++j) {
        float4 g  = gw4[j];
        float4 v0 = *reinterpret_cast<const float4*>(&xs[r0 + 0][dq][j * 4]);
        float4 v1 = *reinterpret_cast<const float4*>(&xs[r0 + 1][dq][j * 4]);
        float4 v2 = *reinterpret_cast<const float4*>(&xs[r0 + 2][dq][j * 4]);
        float4 v3 = *reinterpret_cast<const float4*>(&xs[r0 + 3][dq][j * 4]);
        a0 = fmaf(v0.x, g.x, a0); a0 = fmaf(v0.y, g.y, a0); a0 = fmaf(v0.z, g.z, a0); a0 = fmaf(v0.w, g.w, a0);
        a1 = fmaf(v1.x, g.x, a1); a1 = fmaf(v1.y, g.y, a1); a1 = fmaf(v1.z, g.z, a1); a1 = fmaf(v1.w, g.w, a1);
        a2 = fmaf(v2.x, g.x, a2); a2 = fmaf(v2.y, g.y, a2); a2 = fmaf(v2.z, g.z, a2); a2 = fmaf(v2.w, g.w, a2);
        a3 = fmaf(v3.x, g.x, a3); a3 = fmaf(v3.y, g.y, a3); a3 = fmaf(v3.z, g.z, a3); a3 = fmaf(v3.w, g.w, a3);
    }
    // reduce across the 4 dq groups (every lane ends with full sums)
    a0 += __shfl_xor(a0, 16); a0 += __shfl_xor(a0, 32);
    a1 += __shfl_xor(a1, 16); a1 += __shfl_xor(a1, 32);
    a2 += __shfl_xor(a2, 16); a2 += __shfl_xor(a2, 32);
    a3 += __shfl_xor(a3, 16); a3 += __shfl_xor(a3, 32);

    // each dq group finalizes row r0+dq; all 64 lanes busy
    float sc = (dq == 0) ? a0 : (dq == 1) ? a1 : (dq == 2) ? a2 : a3;
    sc += gbe;

    // 16-lane top-2 (value,index) butterfly; tie -> lower index (matches seq scan)
    float v0 = sc, v1 = -1e30f;
    int   i0 = e,  i1 = 255;
    #pragma unroll
    for (int k = 1; k <= 8; k <<= 1) {
        float o0 = __shfl_xor(v0, k), o1 = __shfl_xor(v1, k);
        int   oi0 = __shfl_xor(i0, k), oi1 = __shfl_xor(i1, k);
        bool gt = (o0 > v0) || (o0 == v0 && oi0 < i0);
        float n0 = gt ? o0 : v0;  int ni0 = gt ? oi0 : i0;
        float c  = gt ? v0 : o0;  int ci  = gt ? i0 : oi0;
        float d  = gt ? o1 : v1;  int di_ = gt ? oi1 : i1;
        bool g2 = (c > d) || (c == d && ci < di_);
        v0 = n0; i0 = ni0;
        v1 = g2 ? c : d;  i1 = g2 ? ci : di_;
    }

    float t = sc - v0;
    float ex = expf(t);
    float Z = ex, S1 = ex * t;
    #pragma unroll
    for (int k = 1; k <= 8; k <<= 1) {
        Z  += __shfl_xor(Z, k);
        S1 += __shfl_xor(S1, k);
    }
    float entloc = logf(Z) - S1 / Z;
    float w0 = 1.0f / (1.0f + expf(v1 - v0));

    if (e == 0) {
        int row = rb + r0 + dq;
        topk_e[row * 2]     = i0;
        topk_e[row * 2 + 1] = i1;
        topk_w[row * 2]     = w0;
        topk_w[row * 2 + 1] = 1.0f - w0;
        int ib = r0 + dq;   // [0,16)
        int lp0 = atomicAdd(&lcnt[i0], 1);
        entpack[ib * 2]     = (row << 1) | (i0 << 15) | (lp0 << 19);
        int lp1 = atomicAdd(&lcnt[i1], 1);
        entpack[ib * 2 + 1] = ((row << 1) | 1) | (i1 << 15) | (lp1 << 19);
        atomicAdd(&entf, entloc);
    }
    __syncthreads();
    if (tid < 16) gbase[tid] = atomicAdd(&cnt[tid], lcnt[tid]);
    if (tid == 0) atomicAdd(ent_acc, entf);
    __syncthreads();
    if (tid < 32) {
        int p = entpack[tid];
        int rowslot = p & 0x7FFF;
        int ee = (p >> 15) & 15;
        int lpos = p >> 19;
        bucket[ee * BROWS + gbase[ee] + lpos] = rowslot;
    }
}

// ---------------- aux loss + dense tile table ----------------
__global__ void aux_kernel(const int* __restrict__ cnt, const float* __restrict__ ent_acc,
                           float* __restrict__ outp, int* __restrict__ tiledesc) {
    __shared__ int off[17];
    int tid = threadIdx.x;
    if (tid == 0) {
        float lb = 0.f;
        for (int k = 0; k < 16; ++k) {
            float u = (float)cnt[k] * (1.f / 16384.f) - 0.0625f;
            lb += u * u;
        }
        lb *= (1.f / 16.f);
        float ment = ent_acc[0] * (1.f / 16384.f);
        outp[0] = lb - 0.1f * ment;
        int o = 0;
        for (int e = 0; e < 16; ++e) { off[e] = o; o += (cnt[e] + 63) >> 6; }
        off[16] = o;
    }
    __syncthreads();
    #pragma unroll 1
    for (int e = 0; e < 16; ++e) {
        int nt = off[e + 1] - off[e];
        for (int i = tid; i < nt; i += 64)
            tiledesc[off[e] + i] = e | (i << 8);
    }
    for (int i = off[16] + tid; i < MAXTILES; i += 64)
        tiledesc[i] = -1;
}

// ---------------- grouped sparse FFN, pipelined, dense tile grid ----------------
__global__ __launch_bounds__(256, 2)
void ffn_kernel(const unsigned short* __restrict__ xb,
                const unsigned short* __restrict__ w1b,   // [E][8][128][64] bf16
                const unsigned short* __restrict__ w2t,   // [E][O][H] bf16
                const float* __restrict__ b1, const float* __restrict__ ln_g,
                const float* __restrict__ ln_b, const float* __restrict__ topk_w,
                const int* __restrict__ cnt, const int* __restrict__ bucket,
                const int* __restrict__ tiledesc,
                unsigned short* __restrict__ contrib) {
    int d = tiledesc[blockIdx.x];
    if (d < 0) return;
    int e = d & 255;
    int t = d >> 8;
    int n = cnt[e];
    int base = t * 64;
    int rows = n - base; if (rows > 64) rows = 64;

    __shared__ __align__(16) char smem[51712];

    const int tid = threadIdx.x;
    const int wave = tid >> 6, lane = tid & 63;
    const int l15 = lane & 15, l4 = lane >> 4;
    const int bbase = e * BROWS + base;

    if (tid < 64) {
        int idx = tid < rows ? tid : (rows - 1);
        int rs = bucket[bbase + idx];
        *(int*)(smem + 51200 + tid * 4) = rs;
        *(float*)(smem + 51456 + tid * 4) = topk_w[rs];
    }

    const int lsw = (((lane & 7) ^ ((lane >> 3) & 7)) << 4);
    int ar0 = wave * 16 + (lane >> 3);
    int ar1 = ar0 + 8;
    size_t grow0 = (size_t)(bucket[bbase + (ar0 < rows ? ar0 : rows - 1)] >> 1) * 1024;
    size_t grow1 = (size_t)(bucket[bbase + (ar1 < rows ? ar1 : rows - 1)] >> 1) * 1024;
    const char* xbp = (const char*)xb;
    const char* w1e = (const char*)w1b + (size_t)e * 131072;
    const char* w2e = (const char*)w2t + (size_t)e * 131072;
    const int sw2e = (((lane & 15) ^ (lane >> 4)) << 4);
    const int sw2o = sw2e ^ 64;

#define STAGE1(ks_, buf_) do { \
    char* ab_ = smem + (buf_) * 8192; \
    char* bb_ = smem + 16384 + (buf_) * 16384; \
    GLD16(xbp + grow0 + (ks_) * 128 + lsw, ab_ + (wave * 2 + 0) * 1024); \
    GLD16(xbp + grow1 + (ks_) * 128 + lsw, ab_ + (wave * 2 + 1) * 1024); \
    const char* s1_ = w1e + (ks_) * 16384 + ((lane >> 3) << 7) + lsw; \
    GLD16(s1_ + (wave * 4 + 0) * 1024, bb_ + (wave * 4 + 0) * 1024); \
    GLD16(s1_ + (wave * 4 + 1) * 1024, bb_ + (wave * 4 + 1) * 1024); \
    GLD16(s1_ + (wave * 4 + 2) * 1024, bb_ + (wave * 4 + 2) * 1024); \
    GLD16(s1_ + (wave * 4 + 3) * 1024, bb_ + (wave * 4 + 3) * 1024); \
} while (0)

#define STAGE2(ns_, buf_) do { \
    char* bb_ = smem + 16384 + (buf_) * 16384; \
    const char* s2_ = w2e + (size_t)(ns_) * 16384 + ((lane >> 4) << 8); \
    GLD16(s2_ + (wave * 4 + 0) * 1024 + sw2e, bb_ + (wave * 4 + 0) * 1024); \
    GLD16(s2_ + (wave * 4 + 1) * 1024 + sw2o, bb_ + (wave * 4 + 1) * 1024); \
    GLD16(s2_ + (wave * 4 + 2) * 1024 + sw2e, bb_ + (wave * 4 + 2) * 1024); \
    GLD16(s2_ + (wave * 4 + 3) * 1024 + sw2o, bb_ + (wave * 4 + 3) * 1024); \
} while (0)

    // ================= GEMM1: h = x_tile @ W1[e] =================
    STAGE1(0, 0);
    f32x4 acc1[4][2];
    #pragma unroll
    for (int r = 0; r < 4; ++r)
        #pragma unroll
        for (int c = 0; c < 2; ++c)
            acc1[r][c] = (f32x4){0.f, 0.f, 0.f, 0.f};

    #pragma unroll
    for (int ks = 0; ks < 8; ++ks) {
        const int cur = ks & 1;
        if (ks < 7) {
            STAGE1(ks + 1, cur ^ 1);
            asm volatile("s_waitcnt vmcnt(6)" ::: "memory");
        } else {
            asm volatile("s_waitcnt vmcnt(0)" ::: "memory");
        }
        asm volatile("s_barrier" ::: "memory");
        const char* ab = smem + cur * 8192;
        const char* bb = smem + 16384 + cur * 16384;
        #pragma unroll
        for (int ks2 = 0; ks2 < 2; ++ks2) {
            const int cb = (((ks2 * 4 + l4) ^ (l15 & 7)) << 4);
            bf16x8 a[4], bg[2];
            #pragma unroll
            for (int r = 0; r < 4; ++r)
                a[r] = *(const bf16x8*)(ab + (r * 16 + l15) * 128 + cb);
            bg[0] = *(const bf16x8*)(bb + (wave * 32 + l15) * 128 + cb);
            bg[1] = *(const bf16x8*)(bb + (wave * 32 + 16 + l15) * 128 + cb);
            #pragma unroll
            for (int r = 0; r < 4; ++r) {
                acc1[r][0] = __builtin_amdgcn_mfma_f32_16x16x32_bf16(a[r], bg[0], acc1[r][0], 0, 0, 0);
                acc1[r][1] = __builtin_amdgcn_mfma_f32_16x16x32_bf16(a[r], bg[1], acc1[r][1], 0, 0, 0);
            }
        }
        asm volatile("s_waitcnt lgkmcnt(0)\n\ts_barrier" ::: "memory");
    }

    // kick off first W2 slice while we do GELU/LN
    STAGE2(0, 0);

    // ================= bias + exact GELU (in regs) + LN partials =================
    const float* b1e = b1 + e * HDIM;
    const int c0 = wave * 32 + l15, c1 = c0 + 16;
    float bias0 = b1e[c0], bias1 = b1e[c1];
    #pragma unroll
    for (int r = 0; r < 4; ++r)
        #pragma unroll
        for (int i = 0; i < 4; ++i) {
            int row = r * 16 + l4 * 4 + i;
            float v0 = acc1[r][0][i] + bias0;
            float v1 = acc1[r][1][i] + bias1;
            v0 = 0.5f * v0 * (1.0f + erff(v0 * 0.70710678f));
            v1 = 0.5f * v1 * (1.0f + erff(v1 * 0.70710678f));
            acc1[r][0][i] = v0; acc1[r][1][i] = v1;
            float s = v0 + v1, ss = v0 * v0 + v1 * v1;
            s  += __shfl_xor(s, 1);  s  += __shfl_xor(s, 2);
            s  += __shfl_xor(s, 4);  s  += __shfl_xor(s, 8);
            ss += __shfl_xor(ss, 1); ss += __shfl_xor(ss, 2);
            ss += __shfl_xor(ss, 4); ss += __shfl_xor(ss, 8);
            if (l15 == 0) {
                *(float*)(smem + 49152 + row * 32 + wave * 8)     = s;
                *(float*)(smem + 49152 + row * 32 + wave * 8 + 4) = ss;
            }
        }
    asm volatile("s_waitcnt lgkmcnt(0)\n\ts_barrier" ::: "memory");

    // ================= LN apply (gate weight folded in) -> h_ln bf16 swizzled =================
    {
        const float* lge = ln_g + e * HDIM;
        const float* lbe = ln_b + e * HDIM;
        float g0 = lge[c0], g1 = lge[c1], be0 = lbe[c0], be1 = lbe[c1];
        #pragma unroll
        for (int r = 0; r < 4; ++r)
            #pragma unroll
            for (int i = 0; i < 4; ++i) {
                int row = r * 16 + l4 * 4 + i;
                float4 p0 = *(const float4*)(smem + 49152 + row * 32);
                float4 p1 = *(const float4*)(smem + 49152 + row * 32 + 16);
                float s  = p0.x + p0.z + p1.x + p1.z;
                float ss = p0.y + p0.w + p1.y + p1.w;
                float mean = s * 0.0078125f;
                float var  = fmaf(-mean, mean, ss * 0.0078125f);
                float rstd = rsqrtf(var + 1e-5f);
                float w = *(const float*)(smem + 51456 + row * 4);
                float h0 = ((acc1[r][0][i] - mean) * rstd * g0 + be0) * w;
                float h1 = ((acc1[r][1][i] - mean) * rstd * g1 + be1) * w;
                int wr = (row & 7) << 4;
                *(unsigned short*)(smem + row * 256 + ((c0 * 2) ^ wr)) = f2bf(h0);
                *(unsigned short*)(smem + row * 256 + ((c1 * 2) ^ wr)) = f2bf(h1);
            }
    }
    asm volatile("s_waitcnt lgkmcnt(0)\n\ts_barrier" ::: "memory");

    // ================= hoist GEMM2 A fragments to registers =================
    bf16x8 A2[4][4];
    #pragma unroll
    for (int r = 0; r < 4; ++r)
        #pragma unroll
        for (int kk = 0; kk < 4; ++kk)
            A2[r][kk] = *(const bf16x8*)(smem + (r * 16 + l15) * 256 + ((((kk * 4 + l4) ^ (l15 & 7))) << 4));
    asm volatile("s_waitcnt lgkmcnt(0)\n\ts_barrier" ::: "memory");   // h_ln region now reusable as patches

    // ================= GEMM2: contrib = h_ln @ W2[e], barrier-free =================
    STAGE2(1, 1);
    char* patch = smem + wave * 3072;   // 64 rows x 48B (16 cols bf16 + pad)
    const int rsoff = (*(const int*)(smem + 51200 + lane * 4)) << 10;
    char* cw = (char*)contrib + rsoff + wave * 32;

    #pragma unroll
    for (int ns = 0; ns < 8; ++ns) {
        if (ns < 7) {
            asm volatile("s_waitcnt lgkmcnt(0)" ::: "memory");
            if (ns > 0) STAGE2(ns + 1, (ns + 1) & 1);
        }
        if (ns == 0)      asm volatile("s_waitcnt vmcnt(4)" ::: "memory");
        else if (ns < 7)  asm volatile("s_waitcnt vmcnt(6)" ::: "memory");
        else              asm volatile("s_waitcnt vmcnt(2)" ::: "memory");

        const char* bb = smem + 16384 + (ns & 1) * 16384;
        bf16x8 Bf[4];
        #pragma unroll
        for (int kk = 0; kk < 4; ++kk)
            Bf[kk] = *(const bf16x8*)(bb + (wave * 16 + l15) * 256 + ((((kk * 4 + l4) ^ (l15 & 7))) << 4));

        f32x4 acc2[4];
        #pragma unroll
        for (int r = 0; r < 4; ++r) acc2[r] = (f32x4){0.f, 0.f, 0.f, 0.f};
        #pragma unroll
        for (int kk = 0; kk < 4; ++kk)
            #pragma unroll
            for (int r = 0; r < 4; ++r)
                acc2[r] = __builtin_amdgcn_mfma_f32_16x16x32_bf16(A2[r][kk], Bf[kk], acc2[r], 0, 0, 0);

        // epilogue through per-wave LDS patch -> 2 vector stores
        #pragma unroll
        for (int r = 0; r < 4; ++r)
            #pragma unroll
            for (int i = 0; i < 4; ++i)
                *(unsigned short*)(patch + (r * 16 + l4 * 4 + i) * 48 + l15 * 2) = f2bf(acc2[r][i]);
        bf16x8 p0 = *(const bf16x8*)(patch + lane * 48);
        bf16x8 p1 = *(const bf16x8*)(patch + lane * 48 + 16);
        *(bf16x8*)(cw + ns * 128)      = p0;
        *(bf16x8*)(cw + ns * 128 + 16) = p1;
    }
#undef STAGE1
#undef STAGE2
}

// ---------------- combine top-2 ----------------
__global__ __launch_bounds__(256)
void combine_kernel(const unsigned short* __restrict__ contrib, const int* __restrict__ topk_e,
                    const float* __restrict__ topk_w, const float* __restrict__ b2,
                    float* __restrict__ out) {
    int idx = blockIdx.x * 256 + threadIdx.x;
    int row = idx >> 6;
    int cb = (idx & 63) << 3;
    int e0 = topk_e[row * 2], e1 = topk_e[row * 2 + 1];
    float w0 = topk_w[row * 2], w1 = topk_w[row * 2 + 1];
    bf16x8 c0 = *reinterpret_cast<const bf16x8*>(contrib + (size_t)row * 1024 + cb);
    bf16x8 c1 = *reinterpret_cast<const bf16x8*>(contrib + (size_t)row * 1024 + 512 + cb);
    const float* b20 = b2 + e0 * ODIM + cb;
    const float* b21 = b2 + e1 * ODIM + cb;
    float res[8];
    #pragma unroll
    for (int j = 0; j < 8; ++j)
        res[j] = bf2f((unsigned short)c0[j]) + bf2f((unsigned short)c1[j]) + w0 * b20[j] + w1 * b21[j];
    float4 o0 = {res[0], res[1], res[2], res[3]};
    float4 o1 = {res[4], res[5], res[6], res[7]};
    *reinterpret_cast<float4*>(out + (size_t)row * ODIM + cb) = o0;
    *reinterpret_cast<float4*>(out + (size_t)row * ODIM + cb + 4) = o1;
}

extern "C" void kernel_launch(void* const* d_in, const int* in_sizes, int n_in,
                              void* d_out, int out_size, void* d_ws, size_t ws_size,
                              hipStream_t stream) {
    const float* x    = (const float*)d_in[0];
    const float* gW   = (const float*)d_in[1];
    const float* gb   = (const float*)d_in[2];
    const float* W1   = (const float*)d_in[3];
    const float* b1   = (const float*)d_in[4];
    const float* ln_g = (const float*)d_in[5];
    const float* ln_b = (const float*)d_in[6];
    const float* W2   = (const float*)d_in[7];
    const float* b2   = (const float*)d_in[8];
    float* out = (float*)d_out;

    char* ws = (char*)d_ws;
    int*   cnt      = (int*)(ws);                    // 64 B
    float* ent_acc  = (float*)(ws + 64);             // 4 B
    int*   tiledesc = (int*)(ws + 128);              // 528*4 = 2112 B
    int*   topk_e   = (int*)(ws + 4096);             // 128 KB
    float* topk_w   = (float*)(ws + 135168);         // 128 KB
    int*   bucket   = (int*)(ws + 266240);           // 1 MB
    unsigned short* xb      = (unsigned short*)(ws + 1314816);   // 16 MB
    unsigned short* w1b     = (unsigned short*)(ws + 18092032);  // 2 MB
    unsigned short* w2t     = (unsigned short*)(ws + 20189184);  // 2 MB
    unsigned short* contrib = (unsigned short*)(ws + 22286336);  // 32 MB
    // gwT (32 KB f32) aliases the head of contrib: gate reads it before ffn writes contrib
    float* gwT = (float*)(ws + 22286336);

    gwt_prep<<<32, 256, 0, stream>>>(gW, gwT, cnt, ent_acc);
    w1_prep<<<dim3(4, 8, NEXP), 256, 0, stream>>>(W1, w1b);
    transpose_to_bf16<<<dim3(ODIM / 32, HDIM / 32, NEXP), dim3(32, 8), 0, stream>>>(W2, w2t, HDIM, ODIM);
    gate_kernel<<<BROWS / 16, 256, 0, stream>>>(x, gwT, gb, cnt, ent_acc, bucket, topk_e, topk_w, xb);
    aux_kernel<<<1, 64, 0, stream>>>(cnt, ent_acc, out + (out_size - 1), tiledesc);
    ffn_kernel<<<MAXTILES, 256, 0, stream>>>(xb, w1b, w2t, b1, ln_g, ln_b, topk_w, cnt, bucket, tiledesc, contrib);
    combine_kernel<<<(BROWS * ODIM / 8) / 256, 256, 0, stream>>>(contrib, topk_e, topk_w, b2, out);
}

// Round 10
// 86.339 us; speedup vs baseline: 1.7768x; 1.1270x over previous
//
#include <hip/hip_runtime.h>

#define BROWS 16384
#define DDIM  512
#define NEXP  16
#define HDIM  128
#define ODIM  512
#define MAXTILES 528

typedef __attribute__((ext_vector_type(8))) short bf16x8;
typedef __attribute__((ext_vector_type(4))) float f32x4;

typedef const __attribute__((address_space(1))) unsigned GA;
typedef __attribute__((address_space(3))) unsigned LA;
#define GLD16(g, l) __builtin_amdgcn_global_load_lds((GA*)(g), (LA*)(l), 16, 0, 0)

static __device__ __forceinline__ unsigned short f2bf(float f) {
    union { float f; unsigned u; } v; v.f = f;
    unsigned r = v.u + 0x7fffu + ((v.u >> 16) & 1u);
    return (unsigned short)(r >> 16);
}
static __device__ __forceinline__ float bf2f(unsigned short h) {
    union { unsigned u; float f; } v; v.u = ((unsigned)h) << 16;
    return v.f;
}

// ---------------- fused prep: gwT transpose + zero cnt/ent + W1 blocking + W2 transpose ----------------
// blocks [0,32): gwT; [32,544): W1 -> [e][ks=8][c=128][k=64]; [544,1568): W2 -> [e][O][H]
__global__ __launch_bounds__(256)
void prep_kernel(const float* __restrict__ gW, float* __restrict__ gwT,
                 int* __restrict__ cnt, float* __restrict__ ent_acc,
                 const float* __restrict__ W1, unsigned short* __restrict__ w1b,
                 const float* __restrict__ W2, unsigned short* __restrict__ w2t) {
    const int b = blockIdx.x;
    const int tid = threadIdx.x;
    if (b < 32) {
        if (b == 0) {
            if (tid < 16) cnt[tid] = 0;
            if (tid == 16) ent_acc[0] = 0.f;
        }
        int i = b * 256 + tid;
        int d = i >> 4, e = i & 15;
        gwT[e * 512 + d] = gW[i];
    } else if (b < 544) {
        __shared__ float tile[64][33];
        int bb = b - 32;
        int e = bb >> 5;
        int rem = bb & 31;
        int ks = rem >> 2;
        int cb = (rem & 3) * 32;
        const float* src = W1 + ((size_t)e * 512 + ks * 64) * 128 + cb;
        int c = tid & 31, r8 = tid >> 5;
        #pragma unroll
        for (int p = 0; p < 8; ++p)
            tile[p * 8 + r8][c] = src[(size_t)(p * 8 + r8) * 128 + c];
        __syncthreads();
        int k = tid & 63, c4 = tid >> 6;
        unsigned short* dst = w1b + (((size_t)e * 8 + ks) * 128 + cb) * 64;
        #pragma unroll
        for (int p = 0; p < 8; ++p)
            dst[(size_t)(c4 + p * 4) * 64 + k] = f2bf(tile[k][c4 + p * 4]);
    } else {
        __shared__ float tile[32][33];
        int bb = b - 544;               // 1024 blocks: e(16) x r0(4) x c0(16); R=128, C=512
        int e = bb >> 6;
        int rem = bb & 63;
        int r0 = (rem >> 4) * 32;
        int c0 = (rem & 15) * 32;
        const float* in = W2 + (size_t)e * HDIM * ODIM;
        unsigned short* out = w2t + (size_t)e * HDIM * ODIM;
        int tx = tid & 31, ty = tid >> 5;
        for (int i = ty; i < 32; i += 8)
            tile[i][tx] = in[(size_t)(r0 + i) * ODIM + c0 + tx];
        __syncthreads();
        for (int i = ty; i < 32; i += 8)
            out[(size_t)(c0 + i) * HDIM + r0 + tx] = f2bf(tile[tx][i]);
    }
}

// ---------------- gating (fused x->bf16), lane = (expert, d-quarter) ----------------
__global__ __launch_bounds__(256)
void gate_kernel(const float* __restrict__ x, const float* __restrict__ gwTg,
                 const float* __restrict__ gb,
                 int* cnt, float* ent_acc, int* bucket, int* topk_e, float* topk_w,
                 unsigned short* __restrict__ xb) {
    __shared__ __align__(16) float xs[16][4][132];   // [row][dq][128+pad]
    __shared__ int lcnt[16];
    __shared__ int gbase[16];
    __shared__ int entpack[32];
    __shared__ float entf;

    const int tid = threadIdx.x;
    const int rb = blockIdx.x * 16;

    // stage x tile (coalesced) + fused bf16 conversion
    #pragma unroll
    for (int k = 0; k < 8; ++k) {
        int idx = tid + k * 256;            // float4 index within [16][128]
        int row = idx >> 7, c4 = idx & 127;
        float4 v = *reinterpret_cast<const float4*>(x + (size_t)(rb + row) * DDIM + c4 * 4);
        int dq = c4 >> 5, j = c4 & 31;
        *reinterpret_cast<float4*>(&xs[row][dq][j * 4]) = v;
        uint2 p;
        p.x = (unsigned)f2bf(v.x) | ((unsigned)f2bf(v.y) << 16);
        p.y = (unsigned)f2bf(v.z) | ((unsigned)f2bf(v.w) << 16);
        *reinterpret_cast<uint2*>(xb + (size_t)(rb + row) * DDIM + c4 * 4) = p;
    }
    if (tid < 16) lcnt[tid] = 0;
    if (tid == 0) entf = 0.f;

    const int wave = tid >> 6, lane = tid & 63;
    const int e = lane & 15, dq = lane >> 4;
    const int r0 = wave * 4;

    const float4* gw4 = reinterpret_cast<const float4*>(gwTg) + e * 128 + dq * 32;
    float gbe = gb[e];
    __syncthreads();

    float a0 = 0.f, a1 = 0.f, a2 = 0.f, a3 = 0.f;
    #pragma unroll
    for (int j = 0; j < 32; ++j) {
        float4 g  = gw4[j];
        float4 v0 = *reinterpret_cast<const float4*>(&xs[r0 + 0][dq][j * 4]);
        float4 v1 = *reinterpret_cast<const float4*>(&xs[r0 + 1][dq][j * 4]);
        float4 v2 = *reinterpret_cast<const float4*>(&xs[r0 + 2][dq][j * 4]);
        float4 v3 = *reinterpret_cast<const float4*>(&xs[r0 + 3][dq][j * 4]);
        a0 = fmaf(v0.x, g.x, a0); a0 = fmaf(v0.y, g.y, a0); a0 = fmaf(v0.z, g.z, a0); a0 = fmaf(v0.w, g.w, a0);
        a1 = fmaf(v1.x, g.x, a1); a1 = fmaf(v1.y, g.y, a1); a1 = fmaf(v1.z, g.z, a1); a1 = fmaf(v1.w, g.w, a1);
        a2 = fmaf(v2.x, g.x, a2); a2 = fmaf(v2.y, g.y, a2); a2 = fmaf(v2.z, g.z, a2); a2 = fmaf(v2.w, g.w, a2);
        a3 = fmaf(v3.x, g.x, a3); a3 = fmaf(v3.y, g.y, a3); a3 = fmaf(v3.z, g.z, a3); a3 = fmaf(v3.w, g.w, a3);
    }
    // reduce across the 4 dq groups (every lane ends with full sums)
    a0 += __shfl_xor(a0, 16); a0 += __shfl_xor(a0, 32);
    a1 += __shfl_xor(a1, 16); a1 += __shfl_xor(a1, 32);
    a2 += __shfl_xor(a2, 16); a2 += __shfl_xor(a2, 32);
    a3 += __shfl_xor(a3, 16); a3 += __shfl_xor(a3, 32);

    // each dq group finalizes row r0+dq; all 64 lanes busy
    float sc = (dq == 0) ? a0 : (dq == 1) ? a1 : (dq == 2) ? a2 : a3;
    sc += gbe;

    // 16-lane top-2 (value,index) butterfly; tie -> lower index (matches seq scan)
    float v0 = sc, v1 = -1e30f;
    int   i0 = e,  i1 = 255;
    #pragma unroll
    for (int k = 1; k <= 8; k <<= 1) {
        float o0 = __shfl_xor(v0, k), o1 = __shfl_xor(v1, k);
        int   oi0 = __shfl_xor(i0, k), oi1 = __shfl_xor(i1, k);
        bool gt = (o0 > v0) || (o0 == v0 && oi0 < i0);
        float n0 = gt ? o0 : v0;  int ni0 = gt ? oi0 : i0;
        float c  = gt ? v0 : o0;  int ci  = gt ? i0 : oi0;
        float d  = gt ? o1 : v1;  int di_ = gt ? oi1 : i1;
        bool g2 = (c > d) || (c == d && ci < di_);
        v0 = n0; i0 = ni0;
        v1 = g2 ? c : d;  i1 = g2 ? ci : di_;
    }

    float t = sc - v0;
    float ex = expf(t);
    float Z = ex, S1 = ex * t;
    #pragma unroll
    for (int k = 1; k <= 8; k <<= 1) {
        Z  += __shfl_xor(Z, k);
        S1 += __shfl_xor(S1, k);
    }
    float entloc = logf(Z) - S1 / Z;
    float w0 = 1.0f / (1.0f + expf(v1 - v0));

    if (e == 0) {
        int row = rb + r0 + dq;
        topk_e[row * 2]     = i0;
        topk_e[row * 2 + 1] = i1;
        topk_w[row * 2]     = w0;
        topk_w[row * 2 + 1] = 1.0f - w0;
        int ib = r0 + dq;   // [0,16)
        int lp0 = atomicAdd(&lcnt[i0], 1);
        entpack[ib * 2]     = (row << 1) | (i0 << 15) | (lp0 << 19);
        int lp1 = atomicAdd(&lcnt[i1], 1);
        entpack[ib * 2 + 1] = ((row << 1) | 1) | (i1 << 15) | (lp1 << 19);
        atomicAdd(&entf, entloc);
    }
    __syncthreads();
    if (tid < 16) gbase[tid] = atomicAdd(&cnt[tid], lcnt[tid]);
    if (tid == 0) atomicAdd(ent_acc, entf);
    __syncthreads();
    if (tid < 32) {
        int p = entpack[tid];
        int rowslot = p & 0x7FFF;
        int ee = (p >> 15) & 15;
        int lpos = p >> 19;
        bucket[ee * BROWS + gbase[ee] + lpos] = rowslot;
    }
}

// ---------------- grouped sparse FFN, pipelined, self-mapped tile grid + aux loss ----------------
__global__ __launch_bounds__(256, 2)
void ffn_kernel(const unsigned short* __restrict__ xb,
                const unsigned short* __restrict__ w1b,   // [E][8][128][64] bf16
                const unsigned short* __restrict__ w2t,   // [E][O][H] bf16
                const float* __restrict__ b1, const float* __restrict__ ln_g,
                const float* __restrict__ ln_b, const float* __restrict__ topk_w,
                const int* __restrict__ cnt, const int* __restrict__ bucket,
                const float* __restrict__ ent_acc, float* __restrict__ outp,
                unsigned short* __restrict__ contrib) {
    const int b = blockIdx.x;
    const int tid = threadIdx.x;

    // self-map block -> (expert, tile) from cnt prefix (uniform scalar work)
    int e = -1, t = 0;
    {
        int o = 0;
        #pragma unroll
        for (int k = 0; k < 16; ++k) {
            int nt = (cnt[k] + 63) >> 6;
            if (b >= o && b < o + nt) { e = k; t = b - o; }
            o += nt;
        }
    }
    if (e < 0) {
        // block MAXTILES-1 is provably always idle (sum of ceil(cnt/64) <= 527): compute aux loss
        if (b == MAXTILES - 1 && tid == 0) {
            float lb = 0.f;
            for (int k = 0; k < 16; ++k) {
                float u = (float)cnt[k] * (1.f / 16384.f) - 0.0625f;
                lb += u * u;
            }
            lb *= (1.f / 16.f);
            outp[0] = lb - 0.1f * (ent_acc[0] * (1.f / 16384.f));
        }
        return;
    }
    int n = cnt[e];
    int base = t * 64;
    int rows = n - base; if (rows > 64) rows = 64;

    __shared__ __align__(16) char smem[51712];

    const int wave = tid >> 6, lane = tid & 63;
    const int l15 = lane & 15, l4 = lane >> 4;
    const int bbase = e * BROWS + base;

    if (tid < 64) {
        int idx = tid < rows ? tid : (rows - 1);
        int rs = bucket[bbase + idx];
        *(int*)(smem + 51200 + tid * 4) = rs;
        *(float*)(smem + 51456 + tid * 4) = topk_w[rs];
    }

    const int lsw = (((lane & 7) ^ ((lane >> 3) & 7)) << 4);
    int ar0 = wave * 16 + (lane >> 3);
    int ar1 = ar0 + 8;
    size_t grow0 = (size_t)(bucket[bbase + (ar0 < rows ? ar0 : rows - 1)] >> 1) * 1024;
    size_t grow1 = (size_t)(bucket[bbase + (ar1 < rows ? ar1 : rows - 1)] >> 1) * 1024;
    const char* xbp = (const char*)xb;
    const char* w1e = (const char*)w1b + (size_t)e * 131072;
    const char* w2e = (const char*)w2t + (size_t)e * 131072;
    const int sw2e = (((lane & 15) ^ (lane >> 4)) << 4);
    const int sw2o = sw2e ^ 64;

#define STAGE1(ks_, buf_) do { \
    char* ab_ = smem + (buf_) * 8192; \
    char* bb_ = smem + 16384 + (buf_) * 16384; \
    GLD16(xbp + grow0 + (ks_) * 128 + lsw, ab_ + (wave * 2 + 0) * 1024); \
    GLD16(xbp + grow1 + (ks_) * 128 + lsw, ab_ + (wave * 2 + 1) * 1024); \
    const char* s1_ = w1e + (ks_) * 16384 + ((lane >> 3) << 7) + lsw; \
    GLD16(s1_ + (wave * 4 + 0) * 1024, bb_ + (wave * 4 + 0) * 1024); \
    GLD16(s1_ + (wave * 4 + 1) * 1024, bb_ + (wave * 4 + 1) * 1024); \
    GLD16(s1_ + (wave * 4 + 2) * 1024, bb_ + (wave * 4 + 2) * 1024); \
    GLD16(s1_ + (wave * 4 + 3) * 1024, bb_ + (wave * 4 + 3) * 1024); \
} while (0)

#define STAGE2(ns_, buf_) do { \
    char* bb_ = smem + 16384 + (buf_) * 16384; \
    const char* s2_ = w2e + (size_t)(ns_) * 16384 + ((lane >> 4) << 8); \
    GLD16(s2_ + (wave * 4 + 0) * 1024 + sw2e, bb_ + (wave * 4 + 0) * 1024); \
    GLD16(s2_ + (wave * 4 + 1) * 1024 + sw2o, bb_ + (wave * 4 + 1) * 1024); \
    GLD16(s2_ + (wave * 4 + 2) * 1024 + sw2e, bb_ + (wave * 4 + 2) * 1024); \
    GLD16(s2_ + (wave * 4 + 3) * 1024 + sw2o, bb_ + (wave * 4 + 3) * 1024); \
} while (0)

    // ================= GEMM1: h = x_tile @ W1[e] =================
    STAGE1(0, 0);
    f32x4 acc1[4][2];
    #pragma unroll
    for (int r = 0; r < 4; ++r)
        #pragma unroll
        for (int c = 0; c < 2; ++c)
            acc1[r][c] = (f32x4){0.f, 0.f, 0.f, 0.f};

    #pragma unroll
    for (int ks = 0; ks < 8; ++ks) {
        const int cur = ks & 1;
        if (ks < 7) {
            STAGE1(ks + 1, cur ^ 1);
            asm volatile("s_waitcnt vmcnt(6)" ::: "memory");
        } else {
            asm volatile("s_waitcnt vmcnt(0)" ::: "memory");
        }
        asm volatile("s_barrier" ::: "memory");
        const char* ab = smem + cur * 8192;
        const char* bb = smem + 16384 + cur * 16384;
        #pragma unroll
        for (int ks2 = 0; ks2 < 2; ++ks2) {
            const int cb = (((ks2 * 4 + l4) ^ (l15 & 7)) << 4);
            bf16x8 a[4], bg[2];
            #pragma unroll
            for (int r = 0; r < 4; ++r)
                a[r] = *(const bf16x8*)(ab + (r * 16 + l15) * 128 + cb);
            bg[0] = *(const bf16x8*)(bb + (wave * 32 + l15) * 128 + cb);
            bg[1] = *(const bf16x8*)(bb + (wave * 32 + 16 + l15) * 128 + cb);
            #pragma unroll
            for (int r = 0; r < 4; ++r) {
                acc1[r][0] = __builtin_amdgcn_mfma_f32_16x16x32_bf16(a[r], bg[0], acc1[r][0], 0, 0, 0);
                acc1[r][1] = __builtin_amdgcn_mfma_f32_16x16x32_bf16(a[r], bg[1], acc1[r][1], 0, 0, 0);
            }
        }
        asm volatile("s_waitcnt lgkmcnt(0)\n\ts_barrier" ::: "memory");
    }

    // kick off first W2 slice while we do GELU/LN
    STAGE2(0, 0);

    // ================= bias + exact GELU (in regs) + LN partials =================
    const float* b1e = b1 + e * HDIM;
    const int c0 = wave * 32 + l15, c1 = c0 + 16;
    float bias0 = b1e[c0], bias1 = b1e[c1];
    #pragma unroll
    for (int r = 0; r < 4; ++r)
        #pragma unroll
        for (int i = 0; i < 4; ++i) {
            int row = r * 16 + l4 * 4 + i;
            float v0 = acc1[r][0][i] + bias0;
            float v1 = acc1[r][1][i] + bias1;
            v0 = 0.5f * v0 * (1.0f + erff(v0 * 0.70710678f));
            v1 = 0.5f * v1 * (1.0f + erff(v1 * 0.70710678f));
            acc1[r][0][i] = v0; acc1[r][1][i] = v1;
            float s = v0 + v1, ss = v0 * v0 + v1 * v1;
            s  += __shfl_xor(s, 1);  s  += __shfl_xor(s, 2);
            s  += __shfl_xor(s, 4);  s  += __shfl_xor(s, 8);
            ss += __shfl_xor(ss, 1); ss += __shfl_xor(ss, 2);
            ss += __shfl_xor(ss, 4); ss += __shfl_xor(ss, 8);
            if (l15 == 0) {
                *(float*)(smem + 49152 + row * 32 + wave * 8)     = s;
                *(float*)(smem + 49152 + row * 32 + wave * 8 + 4) = ss;
            }
        }
    asm volatile("s_waitcnt lgkmcnt(0)\n\ts_barrier" ::: "memory");

    // ================= LN apply (gate weight folded in) -> h_ln bf16 swizzled =================
    {
        const float* lge = ln_g + e * HDIM;
        const float* lbe = ln_b + e * HDIM;
        float g0 = lge[c0], g1 = lge[c1], be0 = lbe[c0], be1 = lbe[c1];
        #pragma unroll
        for (int r = 0; r < 4; ++r)
            #pragma unroll
            for (int i = 0; i < 4; ++i) {
                int row = r * 16 + l4 * 4 + i;
                float4 p0 = *(const float4*)(smem + 49152 + row * 32);
                float4 p1 = *(const float4*)(smem + 49152 + row * 32 + 16);
                float s  = p0.x + p0.z + p1.x + p1.z;
                float ss = p0.y + p0.w + p1.y + p1.w;
                float mean = s * 0.0078125f;
                float var  = fmaf(-mean, mean, ss * 0.0078125f);
                float rstd = rsqrtf(var + 1e-5f);
                float w = *(const float*)(smem + 51456 + row * 4);
                float h0 = ((acc1[r][0][i] - mean) * rstd * g0 + be0) * w;
                float h1 = ((acc1[r][1][i] - mean) * rstd * g1 + be1) * w;
                int wr = (row & 7) << 4;
                *(unsigned short*)(smem + row * 256 + ((c0 * 2) ^ wr)) = f2bf(h0);
                *(unsigned short*)(smem + row * 256 + ((c1 * 2) ^ wr)) = f2bf(h1);
            }
    }
    asm volatile("s_waitcnt lgkmcnt(0)\n\ts_barrier" ::: "memory");

    // ================= hoist GEMM2 A fragments to registers =================
    bf16x8 A2[4][4];
    #pragma unroll
    for (int r = 0; r < 4; ++r)
        #pragma unroll
        for (int kk = 0; kk < 4; ++kk)
            A2[r][kk] = *(const bf16x8*)(smem + (r * 16 + l15) * 256 + ((((kk * 4 + l4) ^ (l15 & 7))) << 4));
    asm volatile("s_waitcnt lgkmcnt(0)\n\ts_barrier" ::: "memory");   // h_ln region now reusable as patches

    // ================= GEMM2: contrib = h_ln @ W2[e], barrier-free =================
    STAGE2(1, 1);
    char* patch = smem + wave * 3072;   // 64 rows x 48B (16 cols bf16 + pad)
    const int rsoff = (*(const int*)(smem + 51200 + lane * 4)) << 10;
    char* cw = (char*)contrib + rsoff + wave * 32;

    #pragma unroll
    for (int ns = 0; ns < 8; ++ns) {
        if (ns < 7) {
            asm volatile("s_waitcnt lgkmcnt(0)" ::: "memory");
            if (ns > 0) STAGE2(ns + 1, (ns + 1) & 1);
        }
        if (ns == 0)      asm volatile("s_waitcnt vmcnt(4)" ::: "memory");
        else if (ns < 7)  asm volatile("s_waitcnt vmcnt(6)" ::: "memory");
        else              asm volatile("s_waitcnt vmcnt(2)" ::: "memory");

        const char* bb = smem + 16384 + (ns & 1) * 16384;
        bf16x8 Bf[4];
        #pragma unroll
        for (int kk = 0; kk < 4; ++kk)
            Bf[kk] = *(const bf16x8*)(bb + (wave * 16 + l15) * 256 + ((((kk * 4 + l4) ^ (l15 & 7))) << 4));

        f32x4 acc2[4];
        #pragma unroll
        for (int r = 0; r < 4; ++r) acc2[r] = (f32x4){0.f, 0.f, 0.f, 0.f};
        #pragma unroll
        for (int kk = 0; kk < 4; ++kk)
            #pragma unroll
            for (int r = 0; r < 4; ++r)
                acc2[r] = __builtin_amdgcn_mfma_f32_16x16x32_bf16(A2[r][kk], Bf[kk], acc2[r], 0, 0, 0);

        // epilogue through per-wave LDS patch -> 2 vector stores
        #pragma unroll
        for (int r = 0; r < 4; ++r)
            #pragma unroll
            for (int i = 0; i < 4; ++i)
                *(unsigned short*)(patch + (r * 16 + l4 * 4 + i) * 48 + l15 * 2) = f2bf(acc2[r][i]);
        bf16x8 p0 = *(const bf16x8*)(patch + lane * 48);
        bf16x8 p1 = *(const bf16x8*)(patch + lane * 48 + 16);
        *(bf16x8*)(cw + ns * 128)      = p0;
        *(bf16x8*)(cw + ns * 128 + 16) = p1;
    }
#undef STAGE1
#undef STAGE2
}

// ---------------- combine top-2 ----------------
__global__ __launch_bounds__(256)
void combine_kernel(const unsigned short* __restrict__ contrib, const int* __restrict__ topk_e,
                    const float* __restrict__ topk_w, const float* __restrict__ b2,
                    float* __restrict__ out) {
    int idx = blockIdx.x * 256 + threadIdx.x;
    int row = idx >> 6;
    int cb = (idx & 63) << 3;
    int e0 = topk_e[row * 2], e1 = topk_e[row * 2 + 1];
    float w0 = topk_w[row * 2], w1 = topk_w[row * 2 + 1];
    bf16x8 c0 = *reinterpret_cast<const bf16x8*>(contrib + (size_t)row * 1024 + cb);
    bf16x8 c1 = *reinterpret_cast<const bf16x8*>(contrib + (size_t)row * 1024 + 512 + cb);
    const float* b20 = b2 + e0 * ODIM + cb;
    const float* b21 = b2 + e1 * ODIM + cb;
    float res[8];
    #pragma unroll
    for (int j = 0; j < 8; ++j)
        res[j] = bf2f((unsigned short)c0[j]) + bf2f((unsigned short)c1[j]) + w0 * b20[j] + w1 * b21[j];
    float4 o0 = {res[0], res[1], res[2], res[3]};
    float4 o1 = {res[4], res[5], res[6], res[7]};
    *reinterpret_cast<float4*>(out + (size_t)row * ODIM + cb) = o0;
    *reinterpret_cast<float4*>(out + (size_t)row * ODIM + cb + 4) = o1;
}

extern "C" void kernel_launch(void* const* d_in, const int* in_sizes, int n_in,
                              void* d_out, int out_size, void* d_ws, size_t ws_size,
                              hipStream_t stream) {
    const float* x    = (const float*)d_in[0];
    const float* gW   = (const float*)d_in[1];
    const float* gb   = (const float*)d_in[2];
    const float* W1   = (const float*)d_in[3];
    const float* b1   = (const float*)d_in[4];
    const float* ln_g = (const float*)d_in[5];
    const float* ln_b = (const float*)d_in[6];
    const float* W2   = (const float*)d_in[7];
    const float* b2   = (const float*)d_in[8];
    float* out = (float*)d_out;

    char* ws = (char*)d_ws;
    int*   cnt      = (int*)(ws);                    // 64 B
    float* ent_acc  = (float*)(ws + 64);             // 4 B
    int*   topk_e   = (int*)(ws + 4096);             // 128 KB
    float* topk_w   = (float*)(ws + 135168);         // 128 KB
    int*   bucket   = (int*)(ws + 266240);           // 1 MB
    unsigned short* xb      = (unsigned short*)(ws + 1314816);   // 16 MB
    unsigned short* w1b     = (unsigned short*)(ws + 18092032);  // 2 MB
    unsigned short* w2t     = (unsigned short*)(ws + 20189184);  // 2 MB
    unsigned short* contrib = (unsigned short*)(ws + 22286336);  // 32 MB
    // gwT (32 KB f32) aliases the head of contrib: gate reads it before ffn writes contrib
    float* gwT = (float*)(ws + 22286336);

    prep_kernel<<<1568, 256, 0, stream>>>(gW, gwT, cnt, ent_acc, W1, w1b, W2, w2t);
    gate_kernel<<<BROWS / 16, 256, 0, stream>>>(x, gwT, gb, cnt, ent_acc, bucket, topk_e, topk_w, xb);
    ffn_kernel<<<MAXTILES, 256, 0, stream>>>(xb, w1b, w2t, b1, ln_g, ln_b, topk_w, cnt, bucket,
                                             ent_acc, out + (out_size - 1), contrib);
    combine_kernel<<<(BROWS * ODIM / 8) / 256, 256, 0, stream>>>(contrib, topk_e, topk_w, b2, out);
}